// Round 14
// baseline (508.123 us; speedup 1.0000x reference)
//
#include <hip/hip_runtime.h>
#include <stdint.h>

// ---------- types & helpers ----------
typedef __bf16 bf16x8 __attribute__((ext_vector_type(8)));
typedef float  f32x4  __attribute__((ext_vector_type(4)));
typedef float  f32x16 __attribute__((ext_vector_type(16)));
typedef unsigned short u16x8 __attribute__((ext_vector_type(8)));

__device__ __forceinline__ unsigned short f2bf(float f) {
    union { float f; uint32_t u; } x; x.f = f;
    uint32_t r = (x.u + 0x7FFFu + ((x.u >> 16) & 1u)) >> 16;
    return (unsigned short)r;
}
__device__ __forceinline__ float bf2f(unsigned short b) {
    union { uint32_t u; float f; } x; x.u = ((uint32_t)b) << 16;
    return x.f;
}

// global -> LDS direct (16B per lane). LDS dest: wave-uniform base + lane*16.
__device__ __forceinline__ void gl16(const void* g, void* l) {
    __builtin_amdgcn_global_load_lds(
        (const __attribute__((address_space(1))) void*)g,
        (__attribute__((address_space(3))) void*)(uint32_t)(uintptr_t)l,
        16, 0, 0);
}

#define MFMA16(a, b, c) __builtin_amdgcn_mfma_f32_16x16x32_bf16((a), (b), (c), 0, 0, 0)
#define MFMA32(a, b, c) __builtin_amdgcn_mfma_f32_32x32x16_bf16((a), (b), (c), 0, 0, 0)

// ---------- merged prep: hs f32->bf16 + 3 weight transposes ----------
__global__ __launch_bounds__(256) void prep_kernel(const float* __restrict__ hs,
                                                   const float* __restrict__ w_qkv,
                                                   const float* __restrict__ w_gate,
                                                   const float* __restrict__ w_out,
                                                   unsigned short* __restrict__ hsb,
                                                   unsigned short* __restrict__ wqt,
                                                   unsigned short* __restrict__ wgt,
                                                   unsigned short* __restrict__ wot) {
    __shared__ float tile[64][65];
    int b = blockIdx.x, tid = threadIdx.x;
    if (b >= 10240) {
        int i = (b - 10240) * 256 + tid;
        float4 a = ((const float4*)hs)[2 * i];
        float4 c = ((const float4*)hs)[2 * i + 1];
        u16x8 o;
        o[0] = f2bf(a.x); o[1] = f2bf(a.y); o[2] = f2bf(a.z); o[3] = f2bf(a.w);
        o[4] = f2bf(c.x); o[5] = f2bf(c.y); o[6] = f2bf(c.z); o[7] = f2bf(c.w);
        ((u16x8*)hsb)[i] = o;
        return;
    }
    const float* in; unsigned short* out; int R, C, bx, by;
    if (b < 6144)      { in = w_qkv;  out = wqt; R = 2048; C = 12288; bx = b % 192; by = b / 192; }
    else if (b < 8192) { int bb = b - 6144; in = w_gate; out = wgt; R = 2048; C = 4096; bx = bb % 64; by = bb / 64; }
    else               { int bb = b - 8192; in = w_out;  out = wot; R = 4096; C = 2048; bx = bb % 32; by = bb / 32; }
    int c0 = bx * 64, r0 = by * 64;
    int tr = tid >> 4;
    int tc4 = (tid & 15) * 4;
#pragma unroll
    for (int it = 0; it < 4; ++it) {
        int r = it * 16 + tr;
        float4 v = *(const float4*)&in[(size_t)(r0 + r) * C + c0 + tc4];
        tile[r][tc4] = v.x; tile[r][tc4 + 1] = v.y;
        tile[r][tc4 + 2] = v.z; tile[r][tc4 + 3] = v.w;
    }
    __syncthreads();
#pragma unroll
    for (int it = 0; it < 4; ++it) {
        int c = it * 16 + tr;
        ushort4 o;
        o.x = f2bf(tile[tc4][c]);
        o.y = f2bf(tile[tc4 + 1][c]);
        o.z = f2bf(tile[tc4 + 2][c]);
        o.w = f2bf(tile[tc4 + 3][c]);
        *(ushort4*)&out[(size_t)(c0 + c) * R + r0 + tc4] = o;
    }
}

// ====== 256x256 4-phase GEMM, fused qkv+gate, 32x32x16 MFMA =================
// R7 schedule preserved: identical staging, read counts, lgkm/vmcnt gates.
// Wave tile per quadrant = 64x32 = 2 MFMA32 tiles; 8 MFMA32 per phase.
// A/B frag: row = base + (lane&31), k = (lane>>5)*8 + elem (bytes (lane>>5)*16).
// C/D: col = lane&31, row = (reg&3) + 8*(reg>>2) + 4*(lane>>5).
__global__ __launch_bounds__(512, 2) void gemm_qkvgate_kernel(const unsigned short* __restrict__ A,
                                                              const unsigned short* __restrict__ Bt,
                                                              unsigned short* __restrict__ qkvp,
                                                              unsigned short* __restrict__ gatep,
                                                              int K, int NBN, int NQ) {
    __shared__ unsigned short Abuf[2][2][8192];
    __shared__ unsigned short Bbuf[2][2][8192];

    int bid = blockIdx.x;
    int xcd = bid & 7, kw = bid >> 3;
    int bm = (xcd & 3) * 4 + (kw & 3);
    int bn = (xcd >> 2) * (NBN >> 1) + (kw >> 2);
    int tid = threadIdx.x, lane = tid & 63, w = tid >> 6;
    int wr = w >> 2, wc = w & 3;

    int r0 = tid >> 3;
    int cbs = (tid & 7) << 4;
    int el0 = (cbs ^ ((r0 & 7) << 4)) >> 1;
    int r1 = 64 + r0;
    int el1 = (cbs ^ ((r1 & 7) << 4)) >> 1;
    int lo0 = tid * 16, lo1 = 8192 + tid * 16;

    const unsigned short* Ag0 = A + (size_t)(bm * 256) * K;
    const unsigned short* Ag1 = A + (size_t)(bm * 256 + 128) * K;
    const unsigned short* Bg0 = Bt + (size_t)(bn * 256) * K;
    const unsigned short* Bg1 = Bt + (size_t)(bn * 256 + 128) * K;

#define STAGE(src, dstHalf, k0)                                            \
    do {                                                                   \
        gl16((src) + (size_t)r0 * K + (k0) + el0, (char*)(dstHalf) + lo0); \
        gl16((src) + (size_t)r1 * K + (k0) + el1, (char*)(dstHalf) + lo1); \
    } while (0)

    int aRow = wr * 64 + (lane & 31);     // +m*32 per frag
    int bRow = wc * 32 + (lane & 31);
    int swzA = (aRow & 7) << 4;
    int swzB = (bRow & 7) << 4;
    int khalf = (lane >> 5) << 4;         // byte offset of k-half

#define RD_A(slot, R, m, kk) \
    af[R][m][kk] = *(const bf16x8*)((const char*)Abuf[slot][R] + ((aRow + (m) * 32) << 7) + (((kk) * 32 + khalf) ^ swzA))
#define RD_B(slot, Cq, kk) \
    bfr[Cq][kk] = *(const bf16x8*)((const char*)Bbuf[slot][Cq] + (bRow << 7) + (((kk) * 32 + khalf) ^ swzB))

#define QUAD(q, Rh, Cc)                                                      \
    do {                                                                     \
        _Pragma("unroll")                                                    \
        for (int kk = 0; kk < 4; ++kk) {                                     \
            acc[q][0] = MFMA32(af[Rh][0][kk], bfr[Cc][kk], acc[q][0]);       \
            acc[q][1] = MFMA32(af[Rh][1][kk], bfr[Cc][kk], acc[q][1]);       \
        }                                                                    \
    } while (0)

    bf16x8 af[2][2][4];    // [half R][m][kk]
    bf16x8 bfr[2][4];      // [half C][kk]
    f32x16 acc[4][2];      // [quad][m]
#pragma unroll
    for (int q = 0; q < 4; ++q)
#pragma unroll
        for (int m = 0; m < 2; ++m)
#pragma unroll
            for (int r = 0; r < 16; ++r) acc[q][m][r] = 0.f;

    int NT = K >> 6;
    STAGE(Ag0, Abuf[0][0], 0);
    STAGE(Bg0, Bbuf[0][0], 0);
    STAGE(Ag1, Abuf[0][1], 0);
    STAGE(Bg1, Bbuf[0][1], 0);
    STAGE(Ag0, Abuf[1][0], 64);
    STAGE(Bg0, Bbuf[1][0], 64);
    STAGE(Ag1, Abuf[1][1], 64);
    STAGE(Bg1, Bbuf[1][1], 64);
    asm volatile("s_waitcnt vmcnt(8)" ::: "memory");
    __builtin_amdgcn_s_barrier();
#pragma unroll
    for (int m = 0; m < 2; ++m)
#pragma unroll
        for (int kk = 0; kk < 4; ++kk) RD_A(0, 0, m, kk);
#pragma unroll
    for (int kk = 0; kk < 4; ++kk) RD_B(0, 0, kk);

    for (int t = 0; t < NT; ++t) {
        int cur = t & 1, nx = cur ^ 1;
        bool rd = (t + 1 < NT);
        bool st = (t + 2 < NT);
        int ks = (t + 2) << 6;

        // ---- PH0: read afR1(t) [8]; Q0 gated on afR0+bC0 (12 older drained)
#pragma unroll
        for (int m = 0; m < 2; ++m)
#pragma unroll
            for (int kk = 0; kk < 4; ++kk) RD_A(cur, 1, m, kk);
        asm volatile("s_waitcnt lgkmcnt(8)" ::: "memory");
        __builtin_amdgcn_sched_barrier(0);
        __builtin_amdgcn_s_setprio(1);
        QUAD(0, 0, 0);
        __builtin_amdgcn_s_setprio(0);

        // ---- PH1: read bC1(t) [4]; Q1 gated on afR1
#pragma unroll
        for (int kk = 0; kk < 4; ++kk) RD_B(cur, 1, kk);
        asm volatile("s_waitcnt lgkmcnt(4)" ::: "memory");
        __builtin_amdgcn_sched_barrier(0);
        __builtin_amdgcn_s_setprio(1);
        QUAD(1, 1, 0);
        __builtin_amdgcn_s_setprio(0);

        // ---- PH2: tile-boundary drain; stage t+2 first half; read bC0(t+1)
        asm volatile("s_waitcnt lgkmcnt(0)" ::: "memory");
        asm volatile("s_waitcnt vmcnt(0)" ::: "memory");
        __builtin_amdgcn_s_barrier();
        if (st) {
            STAGE(Ag0, Abuf[cur][0], ks);
            STAGE(Bg0, Bbuf[cur][0], ks);
        }
        if (rd) {
#pragma unroll
            for (int kk = 0; kk < 4; ++kk) RD_B(nx, 0, kk);
        }
        __builtin_amdgcn_s_setprio(1);
        QUAD(2, 0, 1);
        __builtin_amdgcn_s_setprio(0);

        // ---- PH3: stage t+2 second half; read afR0(t+1); Q3 all-reg
        if (st) {
            STAGE(Ag1, Abuf[cur][1], ks);
            STAGE(Bg1, Bbuf[cur][1], ks);
        }
        if (rd) {
#pragma unroll
            for (int m = 0; m < 2; ++m)
#pragma unroll
                for (int kk = 0; kk < 4; ++kk) RD_A(nx, 0, m, kk);
        }
        __builtin_amdgcn_s_setprio(1);
        QUAD(3, 1, 1);
        __builtin_amdgcn_s_setprio(0);
    }

    // epilogue: block-uniform output select; C/D 32x32 layout
    bool isQ = (bn < NQ);
    unsigned short* outp = isQ ? qkvp : gatep;
    int Nout = isQ ? 12288 : 4096;
    int colb0 = (isQ ? bn : bn - NQ) * 256;
#pragma unroll
    for (int q = 0; q < 4; ++q) {
        const int R_ = q & 1, C_ = q >> 1;
        int col = colb0 + C_ * 128 + wc * 32 + (lane & 31);
#pragma unroll
        for (int m = 0; m < 2; ++m) {
            int rowq = bm * 256 + R_ * 128 + wr * 64 + m * 32 + ((lane >> 5) * 4);
#pragma unroll
            for (int reg = 0; reg < 16; ++reg) {
                int row = rowq + (reg & 3) + 8 * (reg >> 2);
                float v = acc[q][m][reg];
                float sig = 1.f / (1.f + __expf(-v));
                float r = isQ ? v * sig : sig;
                outp[(size_t)row * Nout + col] = f2bf(r);
            }
        }
    }
#undef STAGE
#undef RD_A
#undef RD_B
#undef QUAD
}

// ====== 128x128 pipelined out-GEMM, 32x32x16 MFMA ===========================
__global__ __launch_bounds__(256, 2) void gemm_out_kernel(const unsigned short* __restrict__ A,
                                                          const unsigned short* __restrict__ Bt,
                                                          float* __restrict__ Cout,
                                                          int N, int K, int NBN) {
    __shared__ unsigned short Abuf[2][2][4096];
    __shared__ unsigned short Bbuf[2][2][4096];

    int bid = blockIdx.x;
    int xcd = bid & 7, kw = bid >> 3;
    int bm = (xcd >> 1) * 8 + (kw & 7);
    int bn = (xcd & 1) * 8 + (kw >> 3);
    int tid = threadIdx.x, lane = tid & 63, w = tid >> 6;
    int wr = w >> 1, wc = w & 1;

    int r0 = tid >> 3;
    int cbs = (tid & 7) << 4;
    int el0 = (cbs ^ ((r0 & 7) << 4)) >> 1;
    int r1 = 32 + r0;
    int el1 = (cbs ^ ((r1 & 7) << 4)) >> 1;
    int lo0 = tid * 16, lo1 = 4096 + tid * 16;

    const unsigned short* Ag0 = A + (size_t)(bm * 128) * K;
    const unsigned short* Ag1 = A + (size_t)(bm * 128 + 64) * K;
    const unsigned short* Bg0 = Bt + (size_t)(bn * 128) * K;
    const unsigned short* Bg1 = Bt + (size_t)(bn * 128 + 64) * K;

#define STAGE(src, dstHalf, k0)                                            \
    do {                                                                   \
        gl16((src) + (size_t)r0 * K + (k0) + el0, (char*)(dstHalf) + lo0); \
        gl16((src) + (size_t)r1 * K + (k0) + el1, (char*)(dstHalf) + lo1); \
    } while (0)

    int aRow = wr * 32 + (lane & 31);
    int bRow = wc * 32 + (lane & 31);
    int swzA = (aRow & 7) << 4;
    int swzB = (bRow & 7) << 4;
    int khalf = (lane >> 5) << 4;

#define RD_A(slot, R, kk) \
    af[R][kk] = *(const bf16x8*)((const char*)Abuf[slot][R] + (aRow << 7) + (((kk) * 32 + khalf) ^ swzA))
#define RD_B(slot, Cq, kk) \
    bfr[Cq][kk] = *(const bf16x8*)((const char*)Bbuf[slot][Cq] + (bRow << 7) + (((kk) * 32 + khalf) ^ swzB))

#define QUAD(q, Rh, Cc)                                                      \
    do {                                                                     \
        _Pragma("unroll")                                                    \
        for (int kk = 0; kk < 4; ++kk)                                       \
            acc[q] = MFMA32(af[Rh][kk], bfr[Cc][kk], acc[q]);                \
    } while (0)

    bf16x8 af[2][4];
    bf16x8 bfr[2][4];
    f32x16 acc[4];
#pragma unroll
    for (int q = 0; q < 4; ++q)
#pragma unroll
        for (int r = 0; r < 16; ++r) acc[q][r] = 0.f;

    int NT = K >> 6;
    STAGE(Ag0, Abuf[0][0], 0);
    STAGE(Bg0, Bbuf[0][0], 0);
    STAGE(Ag1, Abuf[0][1], 0);
    STAGE(Bg1, Bbuf[0][1], 0);
    STAGE(Ag0, Abuf[1][0], 64);
    STAGE(Bg0, Bbuf[1][0], 64);
    STAGE(Ag1, Abuf[1][1], 64);
    STAGE(Bg1, Bbuf[1][1], 64);
    asm volatile("s_waitcnt vmcnt(8)" ::: "memory");
    __builtin_amdgcn_s_barrier();
#pragma unroll
    for (int kk = 0; kk < 4; ++kk) { RD_A(0, 0, kk); RD_B(0, 0, kk); }

    for (int t = 0; t < NT; ++t) {
        int cur = t & 1, nx = cur ^ 1;
        bool rd = (t + 1 < NT);
        bool st = (t + 2 < NT);
        int ks = (t + 2) << 6;

        // ---- PH0
#pragma unroll
        for (int kk = 0; kk < 4; ++kk) RD_A(cur, 1, kk);
        asm volatile("s_waitcnt lgkmcnt(4)" ::: "memory");
        __builtin_amdgcn_sched_barrier(0);
        __builtin_amdgcn_s_setprio(1);
        QUAD(0, 0, 0);
        __builtin_amdgcn_s_setprio(0);

        // ---- PH1
#pragma unroll
        for (int kk = 0; kk < 4; ++kk) RD_B(cur, 1, kk);
        asm volatile("s_waitcnt lgkmcnt(4)" ::: "memory");
        __builtin_amdgcn_sched_barrier(0);
        __builtin_amdgcn_s_setprio(1);
        QUAD(1, 1, 0);
        __builtin_amdgcn_s_setprio(0);

        // ---- PH2: single tile-boundary drain
        asm volatile("s_waitcnt lgkmcnt(0)" ::: "memory");
        asm volatile("s_waitcnt vmcnt(0)" ::: "memory");
        __builtin_amdgcn_s_barrier();
        if (st) {
            STAGE(Ag0, Abuf[cur][0], ks);
            STAGE(Bg0, Bbuf[cur][0], ks);
        }
        if (rd) {
#pragma unroll
            for (int kk = 0; kk < 4; ++kk) RD_B(nx, 0, kk);
        }
        __builtin_amdgcn_s_setprio(1);
        QUAD(2, 0, 1);
        __builtin_amdgcn_s_setprio(0);

        // ---- PH3
        if (st) {
            STAGE(Ag1, Abuf[cur][1], ks);
            STAGE(Bg1, Bbuf[cur][1], ks);
        }
        if (rd) {
#pragma unroll
            for (int kk = 0; kk < 4; ++kk) RD_A(nx, 0, kk);
        }
        __builtin_amdgcn_s_setprio(1);
        QUAD(3, 1, 1);
        __builtin_amdgcn_s_setprio(0);
    }

    // epilogue (f32 out), 32x32 C/D layout
#pragma unroll
    for (int q = 0; q < 4; ++q) {
        const int R_ = q & 1, C_ = q >> 1;
        int col = bn * 128 + C_ * 64 + wc * 32 + (lane & 31);
        int rowq = bm * 128 + R_ * 64 + wr * 32 + ((lane >> 5) * 4);
#pragma unroll
        for (int reg = 0; reg < 16; ++reg) {
            int row = rowq + (reg & 3) + 8 * (reg >> 2);
            Cout[(size_t)row * N + col] = acc[q][reg];
        }
    }
#undef STAGE
#undef RD_A
#undef RD_B
#undef QUAD
}

// ---------- qkv -> kts (scaled, transposed), vt (transposed); 64x64 tiles ----------
__global__ __launch_bounds__(256) void kv_transpose_kernel(const unsigned short* __restrict__ qkv,
                                                           const float* __restrict__ slopes,
                                                           unsigned short* __restrict__ kts,
                                                           unsigned short* __restrict__ vt) {
    __shared__ unsigned short tk[64][66];
    __shared__ unsigned short tv[64][66];
    int n0 = blockIdx.x * 64, d0 = blockIdx.y * 64, h = blockIdx.z;
    float s = slopes[h];
    int tid = threadIdx.x;
    int tr = tid >> 4;
    int tc4 = (tid & 15) * 4;
#pragma unroll
    for (int it = 0; it < 4; ++it) {
        int r = it * 16 + tr;
        int n = n0 + r;
        size_t rowb = (size_t)n * 12288 + h * 384;
        float sc = __expf(-s * (float)(255 - (n & 255)));
        ushort4 k4 = *(const ushort4*)&qkv[rowb + 128 + d0 + tc4];
        ushort4 v4 = *(const ushort4*)&qkv[rowb + 256 + d0 + tc4];
        tk[r][tc4 + 0] = f2bf(bf2f(k4.x) * sc);
        tk[r][tc4 + 1] = f2bf(bf2f(k4.y) * sc);
        tk[r][tc4 + 2] = f2bf(bf2f(k4.z) * sc);
        tk[r][tc4 + 3] = f2bf(bf2f(k4.w) * sc);
        tv[r][tc4 + 0] = v4.x;
        tv[r][tc4 + 1] = v4.y;
        tv[r][tc4 + 2] = v4.z;
        tv[r][tc4 + 3] = v4.w;
    }
    __syncthreads();
#pragma unroll
    for (int it = 0; it < 4; ++it) {
        int c = it * 16 + tr;
        ushort4 ok, ov;
        ok.x = tk[tc4 + 0][c]; ok.y = tk[tc4 + 1][c];
        ok.z = tk[tc4 + 2][c]; ok.w = tk[tc4 + 3][c];
        ov.x = tv[tc4 + 0][c]; ov.y = tv[tc4 + 1][c];
        ov.z = tv[tc4 + 2][c]; ov.w = tv[tc4 + 3][c];
        size_t ob = (size_t)(h * 128 + d0 + c) * 4096 + n0 + tc4;
        *(ushort4*)&kts[ob] = ok;
        *(ushort4*)&vt[ob] = ov;
    }
}

// ---------- per-block KV outer product ----------
__global__ __launch_bounds__(256) void kv_outer_kernel(const unsigned short* __restrict__ kts,
                                                       const unsigned short* __restrict__ vt,
                                                       float* __restrict__ U) {
    __shared__ unsigned short Kc[128 * 64];
    __shared__ unsigned short Vc[128 * 64];
    int blk = blockIdx.x;
    int h = blk & 31, t = blk >> 5;
    int tid = threadIdx.x, lane = tid & 63, w = tid >> 6;

    f32x4 acc[2][8];
#pragma unroll
    for (int m = 0; m < 2; ++m)
#pragma unroll
        for (int n = 0; n < 8; ++n)
#pragma unroll
            for (int r = 0; r < 4; ++r) acc[m][n][r] = 0.f;

    for (int ks = 0; ks < 4; ++ks) {
        __syncthreads();
#pragma unroll
        for (int it = 0; it < 4; ++it) {
            int slot = it * 256 + tid;
            int o = slot * 16;
            int r = o >> 7;
            int cb = o & 127;
            int scb = cb ^ ((r & 7) << 4);
            size_t j = (size_t)t * 256 + ks * 64 + (scb >> 1);
            gl16(kts + (size_t)(h * 128 + r) * 4096 + j, (char*)Kc + o);
            gl16(vt + (size_t)(h * 128 + r) * 4096 + j, (char*)Vc + o);
        }
        __syncthreads();
#pragma unroll
        for (int kk = 0; kk < 2; ++kk) {
            int kb = kk * 64 + ((lane >> 4) * 16);
            bf16x8 vf[2], kf[8];
#pragma unroll
            for (int m = 0; m < 2; ++m) {
                int e = w * 32 + m * 16 + (lane & 15);
                vf[m] = *(const bf16x8*)((const char*)Vc + (e << 7) + (kb ^ ((e & 7) << 4)));
            }
#pragma unroll
            for (int n = 0; n < 8; ++n) {
                int d = n * 16 + (lane & 15);
                kf[n] = *(const bf16x8*)((const char*)Kc + (d << 7) + (kb ^ ((d & 7) << 4)));
            }
#pragma unroll
            for (int m = 0; m < 2; ++m)
#pragma unroll
                for (int n = 0; n < 8; ++n)
                    acc[m][n] = MFMA16(vf[m], kf[n], acc[m][n]);
        }
    }
    size_t base = (size_t)(h * 16 + t) * 16384;
#pragma unroll
    for (int m = 0; m < 2; ++m)
#pragma unroll
        for (int n = 0; n < 8; ++n)
#pragma unroll
            for (int r = 0; r < 4; ++r) {
                int e = w * 32 + m * 16 + ((lane >> 4) * 4) + r;
                int d = n * 16 + (lane & 15);
                U[base + (size_t)e * 128 + d] = acc[m][n][r];
            }
}

// ---------- parallel scan: 32 heads x 16 chunks of 1024 ----------
__global__ __launch_bounds__(256) void kv_scan_kernel(const float* __restrict__ kv_cache,
                                                      const float* __restrict__ U,
                                                      const float* __restrict__ slopes,
                                                      unsigned short* __restrict__ Wb) {
    __shared__ float Tt[8][132];
    int h = blockIdx.x >> 4;
    int c = blockIdx.x & 15;
    int c0 = c * 1024, e0 = c * 8;
    int tid = threadIdx.x;
    float s = slopes[h];
    float bd = __expf(-s * 256.f);
    size_t hb = (size_t)h * 16384;
#pragma unroll
    for (int it = 0; it < 4; ++it) {
        int d = it * 32 + (tid >> 3);
        Tt[tid & 7][d] = kv_cache[hb + (size_t)d * 128 + e0 + (tid & 7)];
    }
    __syncthreads();
    float wst[4];
#pragma unroll
    for (int i = 0; i < 4; ++i) {
        int local = i * 256 + tid;
        wst[i] = Tt[local >> 7][local & 127];
    }
    for (int t = 0; t < 16; ++t) {
        size_t base = (size_t)(h * 16 + t) * 16384 + c0;
#pragma unroll
        for (int i = 0; i < 4; ++i) {
            int idx = i * 256 + tid;
            Wb[base + idx] = f2bf(wst[i]);
            wst[i] = bd * wst[i] + U[base + idx];
        }
    }
}

// ---------- fused attention block kernel: QBLK=128, 80KB LDS, 2 WG/CU ----------
__global__ __launch_bounds__(256, 2) void attn_out_kernel(const unsigned short* __restrict__ qkv,
                                                          const unsigned short* __restrict__ vt,
                                                          const unsigned short* __restrict__ Wb,
                                                          const float* __restrict__ slopes,
                                                          unsigned short* __restrict__ attn) {
    __shared__ unsigned short lds[40960];  // 80 KB
    unsigned short* Qs = lds;
    unsigned short* Ps = lds + 16384;
    unsigned short* KW = lds + 24576;
    unsigned short* Ks = KW;
    unsigned short* Vs = KW + 8192;

    int bid = blockIdx.x;
    int kw = bid >> 3;
    int h = (bid & 7) * 4 + (kw & 3);
    int tq = kw >> 2;
    int t = tq >> 1, qh = tq & 1;
    float s = slopes[h];
    int tid = threadIdx.x, lane = tid & 63, w = tid >> 6;
    int rowbase = t * 256 + qh * 128;

#pragma unroll
    for (int it = 0; it < 8; ++it) {
        int o = (it * 256 + tid) * 16;
        int r = o >> 8, cb = o & 255, scb = cb ^ ((r & 7) << 4);
        gl16(qkv + (size_t)(rowbase + r) * 12288 + h * 384 + (scb >> 1), (char*)Qs + o);
    }
#pragma unroll
    for (int it = 0; it < 8; ++it) {
        int o = (it * 256 + tid) * 16;
        int e = o >> 8, cb = o & 255, scb = cb ^ ((e & 7) << 4);
        gl16(Wb + (size_t)((h * 16 + t) * 128 + e) * 128 + (scb >> 1), (char*)KW + o);
    }
    __syncthreads();

    f32x4 acc[2][8];
#pragma unroll
    for (int m = 0; m < 2; ++m)
#pragma unroll
        for (int n = 0; n < 8; ++n)
#pragma unroll
            for (int r = 0; r < 4; ++r) acc[m][n][r] = 0.f;

#pragma unroll
    for (int kk = 0; kk < 4; ++kk) {
        int kb = kk * 64 + ((lane >> 4) * 16);
        bf16x8 qf[2], wf[8];
#pragma unroll
        for (int m = 0; m < 2; ++m) {
            int r = w * 32 + m * 16 + (lane & 15);
            qf[m] = *(const bf16x8*)((const char*)Qs + (r << 8) + (kb ^ ((r & 7) << 4)));
        }
#pragma unroll
        for (int n = 0; n < 8; ++n) {
            int e = n * 16 + (lane & 15);
            wf[n] = *(const bf16x8*)((const char*)KW + (e << 8) + (kb ^ ((e & 7) << 4)));
        }
#pragma unroll
        for (int m = 0; m < 2; ++m)
#pragma unroll
            for (int n = 0; n < 8; ++n)
                acc[m][n] = MFMA16(qf[m], wf[n], acc[m][n]);
    }
#pragma unroll
    for (int m = 0; m < 2; ++m)
#pragma unroll
        for (int rg = 0; rg < 4; ++rg) {
            int i = qh * 128 + w * 32 + m * 16 + ((lane >> 4) * 4) + rg;
            float qd = __expf(-s * (float)(i + 1));
#pragma unroll
            for (int n = 0; n < 8; ++n) acc[m][n][rg] *= qd;
        }

    int jbmax = ((qh << 2) + w) >> 1;
    int jbend = qh ? 4 : 2;
    for (int jb = 0; jb < jbend; ++jb) {
        __syncthreads();
#pragma unroll
        for (int it = 0; it < 4; ++it) {
            int o = (it * 256 + tid) * 16;
            int r = o >> 8, cb = o & 255, scb = cb ^ ((r & 7) << 4);
            gl16(qkv + (size_t)(t * 256 + jb * 64 + r) * 12288 + h * 384 + 128 + (scb >> 1),
                 (char*)Ks + o);
        }
#pragma unroll
        for (int it = 0; it < 4; ++it) {
            int o = (it * 256 + tid) * 16;
            int e = o >> 7, cb = o & 127, scb = cb ^ ((e & 7) << 4);
            gl16(vt + (size_t)(h * 128 + e) * 4096 + t * 256 + jb * 64 + (scb >> 1),
                 (char*)Vs + o);
        }
        __syncthreads();

        if (jb <= jbmax) {
            f32x4 sc[2][4];
#pragma unroll
            for (int m = 0; m < 2; ++m)
#pragma unroll
                for (int n = 0; n < 4; ++n)
#pragma unroll
                    for (int r = 0; r < 4; ++r) sc[m][n][r] = 0.f;
#pragma unroll
            for (int kk = 0; kk < 4; ++kk) {
                int kb = kk * 64 + ((lane >> 4) * 16);
                bf16x8 qf[2], kf[4];
#pragma unroll
                for (int m = 0; m < 2; ++m) {
                    int r = w * 32 + m * 16 + (lane & 15);
                    qf[m] = *(const bf16x8*)((const char*)Qs + (r << 8) + (kb ^ ((r & 7) << 4)));
                }
#pragma unroll
                for (int n = 0; n < 4; ++n) {
                    int r = n * 16 + (lane & 15);
                    kf[n] = *(const bf16x8*)((const char*)Ks + (r << 8) + (kb ^ ((r & 7) << 4)));
                }
#pragma unroll
                for (int m = 0; m < 2; ++m)
#pragma unroll
                    for (int n = 0; n < 4; ++n)
                        sc[m][n] = MFMA16(qf[m], kf[n], sc[m][n]);
            }
            unsigned short* Pw = Ps + w * 2048;
#pragma unroll
            for (int m = 0; m < 2; ++m)
#pragma unroll
                for (int n = 0; n < 4; ++n)
#pragma unroll
                    for (int rg = 0; rg < 4; ++rg) {
                        int il = m * 16 + ((lane >> 4) * 4) + rg;
                        int i = qh * 128 + w * 32 + il;
                        int jl = n * 16 + (lane & 15);
                        int j = jb * 64 + jl;
                        float v = 0.f;
                        if (i >= j) v = sc[m][n][rg] * __expf(-s * (float)(i - j));
                        int cb2 = (jl * 2) ^ ((il & 7) << 4);
                        *(unsigned short*)((char*)Pw + (il << 7) + cb2) = f2bf(v);
                    }
            asm volatile("s_waitcnt lgkmcnt(0)" ::: "memory");
#pragma unroll
            for (int kk = 0; kk < 2; ++kk) {
                int kb = kk * 64 + ((lane >> 4) * 16);
                bf16x8 pf[2], vf[8];
#pragma unroll
                for (int m = 0; m < 2; ++m) {
                    int il = m * 16 + (lane & 15);
                    pf[m] = *(const bf16x8*)((const char*)Pw + (il << 7) + (kb ^ ((il & 7) << 4)));
                }
#pragma unroll
                for (int n = 0; n < 8; ++n) {
                    int e = n * 16 + (lane & 15);
                    vf[n] = *(const bf16x8*)((const char*)Vs + (e << 7) + (kb ^ ((e & 7) << 4)));
                }
#pragma unroll
                for (int m = 0; m < 2; ++m)
#pragma unroll
                    for (int n = 0; n < 8; ++n)
                        acc[m][n] = MFMA16(pf[m], vf[n], acc[m][n]);
            }
        }
    }

#pragma unroll
    for (int m = 0; m < 2; ++m)
#pragma unroll
        for (int n = 0; n < 8; ++n)
#pragma unroll
            for (int rg = 0; rg < 4; ++rg) {
                int i = qh * 128 + w * 32 + m * 16 + ((lane >> 4) * 4) + rg;
                int col = h * 128 + n * 16 + (lane & 15);
                attn[(size_t)(t * 256 + i) * 4096 + col] = f2bf(acc[m][n][rg]);
            }
}

// ---------- RMSNorm + sigmoid-gate multiply ----------
__global__ __launch_bounds__(256) void rms_gate_kernel(const unsigned short* __restrict__ attn,
                                                       const unsigned short* __restrict__ gate,
                                                       const float* __restrict__ nw,
                                                       unsigned short* __restrict__ gated) {
    int row = blockIdx.x, tid = threadIdx.x;
    int lane = tid & 63, w = tid >> 6;
    const unsigned short* ar = attn + (size_t)row * 4096 + tid * 16;
    u16x8 a0 = *(const u16x8*)ar;
    u16x8 a1 = *(const u16x8*)(ar + 8);
    float v[16];
    float ss = 0.f;
#pragma unroll
    for (int j = 0; j < 8; ++j) { v[j] = bf2f(a0[j]); v[8 + j] = bf2f(a1[j]); }
#pragma unroll
    for (int j = 0; j < 16; ++j) ss += v[j] * v[j];
#pragma unroll
    for (int o = 32; o > 0; o >>= 1) ss += __shfl_xor(ss, o);
    __shared__ float red[4];
    if (lane == 0) red[w] = ss;
    __syncthreads();
    float tot = red[0] + red[1] + red[2] + red[3];
    float rs = rsqrtf(tot * (1.f / 4096.f) + 1e-5f);
    const unsigned short* gr = gate + (size_t)row * 4096 + tid * 16;
    u16x8 g0 = *(const u16x8*)gr;
    u16x8 g1 = *(const u16x8*)(gr + 8);
    const float* nwp = nw + tid * 16;
    u16x8 o0, o1;
#pragma unroll
    for (int j = 0; j < 8; ++j) {
        o0[j] = f2bf(v[j] * rs * nwp[j] * bf2f(g0[j]));
        o1[j] = f2bf(v[8 + j] * rs * nwp[8 + j] * bf2f(g1[j]));
    }
    unsigned short* gp = gated + (size_t)row * 4096 + tid * 16;
    *(u16x8*)gp = o0;
    *(u16x8*)(gp + 8) = o1;
}

// ---------- launcher ----------
extern "C" void kernel_launch(void* const* d_in, const int* in_sizes, int n_in,
                              void* d_out, int out_size, void* d_ws, size_t ws_size,
                              hipStream_t stream) {
    const float* hs       = (const float*)d_in[0];
    const float* w_qkv    = (const float*)d_in[1];
    const float* w_gate   = (const float*)d_in[2];
    const float* w_out    = (const float*)d_in[3];
    const float* nw       = (const float*)d_in[4];
    const float* slopes   = (const float*)d_in[5];
    const float* kv_cache = (const float*)d_in[6];
    float* out = (float*)d_out;
    char* ws = (char*)d_ws;

    unsigned short* hsb  = (unsigned short*)(ws + 0);
    unsigned short* wqt  = (unsigned short*)(ws + 16777216);
    unsigned short* wgt  = (unsigned short*)(ws + 67108864);
    unsigned short* wot  = (unsigned short*)(ws + 83886080);
    unsigned short* qkv  = (unsigned short*)(ws + 100663296);
    unsigned short* gate = (unsigned short*)(ws + 201326592);
    unsigned short* kts  = (unsigned short*)(ws + 234881024);
    unsigned short* vt   = (unsigned short*)(ws + 268435456);
    float*          U    = (float*)(ws + 301989888);
    unsigned short* Wb   = (unsigned short*)(ws + 335544320);
    unsigned short* attn  = wqt;  // reuse
    unsigned short* gated = qkv;  // reuse

    prep_kernel<<<14336, 256, 0, stream>>>(hs, w_qkv, w_gate, w_out, hsb, wqt, wgt, wot);
    gemm_qkvgate_kernel<<<1024, 512, 0, stream>>>(hsb, wqt, qkv, gate, 2048, 64, 48);
    {
        dim3 g(64, 2, 32);
        kv_transpose_kernel<<<g, 256, 0, stream>>>(qkv, slopes, kts, vt);
    }
    kv_outer_kernel<<<512, 256, 0, stream>>>(kts, vt, U);
    kv_scan_kernel<<<512, 256, 0, stream>>>(kv_cache, U, slopes, Wb);
    attn_out_kernel<<<1024, 256, 0, stream>>>(qkv, vt, Wb, slopes, attn);
    rms_gate_kernel<<<4096, 256, 0, stream>>>(attn, gate, nw, gated);
    gemm_out_kernel<<<512, 256, 0, stream>>>(gated, wot, out, 2048, 4096, 16);
}

// Round 15
// 467.285 us; speedup vs baseline: 1.0874x; 1.0874x over previous
//
#include <hip/hip_runtime.h>
#include <stdint.h>

// ---------- types & helpers ----------
typedef __bf16 bf16x8 __attribute__((ext_vector_type(8)));
typedef float  f32x4  __attribute__((ext_vector_type(4)));
typedef unsigned short u16x8 __attribute__((ext_vector_type(8)));

__device__ __forceinline__ unsigned short f2bf(float f) {
    union { float f; uint32_t u; } x; x.f = f;
    uint32_t r = (x.u + 0x7FFFu + ((x.u >> 16) & 1u)) >> 16;
    return (unsigned short)r;
}
__device__ __forceinline__ float bf2f(unsigned short b) {
    union { uint32_t u; float f; } x; x.u = ((uint32_t)b) << 16;
    return x.f;
}

// global -> LDS direct (16B per lane). LDS dest: wave-uniform base + lane*16.
__device__ __forceinline__ void gl16(const void* g, void* l) {
    __builtin_amdgcn_global_load_lds(
        (const __attribute__((address_space(1))) void*)g,
        (__attribute__((address_space(3))) void*)(uint32_t)(uintptr_t)l,
        16, 0, 0);
}

#define MFMA16(a, b, c) __builtin_amdgcn_mfma_f32_16x16x32_bf16((a), (b), (c), 0, 0, 0)

// ---------- merged prep: hs f32->bf16 + 3 weight transposes ----------
__global__ __launch_bounds__(256) void prep_kernel(const float* __restrict__ hs,
                                                   const float* __restrict__ w_qkv,
                                                   const float* __restrict__ w_gate,
                                                   const float* __restrict__ w_out,
                                                   unsigned short* __restrict__ hsb,
                                                   unsigned short* __restrict__ wqt,
                                                   unsigned short* __restrict__ wgt,
                                                   unsigned short* __restrict__ wot) {
    __shared__ float tile[64][65];
    int b = blockIdx.x, tid = threadIdx.x;
    if (b >= 10240) {
        int i = (b - 10240) * 256 + tid;
        float4 a = ((const float4*)hs)[2 * i];
        float4 c = ((const float4*)hs)[2 * i + 1];
        u16x8 o;
        o[0] = f2bf(a.x); o[1] = f2bf(a.y); o[2] = f2bf(a.z); o[3] = f2bf(a.w);
        o[4] = f2bf(c.x); o[5] = f2bf(c.y); o[6] = f2bf(c.z); o[7] = f2bf(c.w);
        ((u16x8*)hsb)[i] = o;
        return;
    }
    const float* in; unsigned short* out; int R, C, bx, by;
    if (b < 6144)      { in = w_qkv;  out = wqt; R = 2048; C = 12288; bx = b % 192; by = b / 192; }
    else if (b < 8192) { int bb = b - 6144; in = w_gate; out = wgt; R = 2048; C = 4096; bx = bb % 64; by = bb / 64; }
    else               { int bb = b - 8192; in = w_out;  out = wot; R = 4096; C = 2048; bx = bb % 32; by = bb / 32; }
    int c0 = bx * 64, r0 = by * 64;
    int tr = tid >> 4;
    int tc4 = (tid & 15) * 4;
#pragma unroll
    for (int it = 0; it < 4; ++it) {
        int r = it * 16 + tr;
        float4 v = *(const float4*)&in[(size_t)(r0 + r) * C + c0 + tc4];
        tile[r][tc4] = v.x; tile[r][tc4 + 1] = v.y;
        tile[r][tc4 + 2] = v.z; tile[r][tc4 + 3] = v.w;
    }
    __syncthreads();
#pragma unroll
    for (int it = 0; it < 4; ++it) {
        int c = it * 16 + tr;
        ushort4 o;
        o.x = f2bf(tile[tc4][c]);
        o.y = f2bf(tile[tc4 + 1][c]);
        o.z = f2bf(tile[tc4 + 2][c]);
        o.w = f2bf(tile[tc4 + 3][c]);
        *(ushort4*)&out[(size_t)(c0 + c) * R + r0 + tc4] = o;
    }
}

// ====== 256x256 register-pipelined 4-phase GEMM, fused qkv+gate (R10) =======
__global__ __launch_bounds__(512, 2) void gemm_qkvgate_kernel(const unsigned short* __restrict__ A,
                                                              const unsigned short* __restrict__ Bt,
                                                              unsigned short* __restrict__ qkvp,
                                                              unsigned short* __restrict__ gatep,
                                                              int K, int NBN, int NQ) {
    __shared__ unsigned short Abuf[2][2][8192];
    __shared__ unsigned short Bbuf[2][2][8192];

    int bid = blockIdx.x;
    int xcd = bid & 7, kw = bid >> 3;
    int bm = (xcd & 3) * 4 + (kw & 3);
    int bn = (xcd >> 2) * (NBN >> 1) + (kw >> 2);
    int tid = threadIdx.x, lane = tid & 63, w = tid >> 6;
    int wr = w >> 2, wc = w & 3;

    int r0 = tid >> 3;
    int cbs = (tid & 7) << 4;
    int el0 = (cbs ^ ((r0 & 7) << 4)) >> 1;
    int r1 = 64 + r0;
    int el1 = (cbs ^ ((r1 & 7) << 4)) >> 1;
    int lo0 = tid * 16, lo1 = 8192 + tid * 16;

    const unsigned short* Ag0 = A + (size_t)(bm * 256) * K;
    const unsigned short* Ag1 = A + (size_t)(bm * 256 + 128) * K;
    const unsigned short* Bg0 = Bt + (size_t)(bn * 256) * K;
    const unsigned short* Bg1 = Bt + (size_t)(bn * 256 + 128) * K;

#define STAGE(src, dstHalf, k0)                                            \
    do {                                                                   \
        gl16((src) + (size_t)r0 * K + (k0) + el0, (char*)(dstHalf) + lo0); \
        gl16((src) + (size_t)r1 * K + (k0) + el1, (char*)(dstHalf) + lo1); \
    } while (0)

    int aRow = wr * 64 + (lane & 15);
    int bRow = wc * 32 + (lane & 15);
    int swz = (lane & 7) << 4;
    int cbb = (lane >> 4) << 4;

#define RD_A(slot, R, m, kk) \
    af[R][m][kk] = *(const bf16x8*)((const char*)Abuf[slot][R] + ((aRow + (m) * 16) << 7) + (((kk) * 64 + cbb) ^ swz))
#define RD_B(slot, Cq, n, kk) \
    bfr[Cq][n][kk] = *(const bf16x8*)((const char*)Bbuf[slot][Cq] + ((bRow + (n) * 16) << 7) + (((kk) * 64 + cbb) ^ swz))

#define QUAD(q, Rh, Cc)                                                       \
    do {                                                                      \
        _Pragma("unroll")                                                     \
        for (int m = 0; m < 4; ++m)                                           \
            _Pragma("unroll")                                                 \
            for (int n = 0; n < 2; ++n) {                                     \
                acc[q][m][n] = MFMA16(af[Rh][m][0], bfr[Cc][n][0], acc[q][m][n]); \
                acc[q][m][n] = MFMA16(af[Rh][m][1], bfr[Cc][n][1], acc[q][m][n]); \
            }                                                                 \
    } while (0)

    bf16x8 af[2][4][2];
    bf16x8 bfr[2][2][2];
    f32x4 acc[4][4][2];
#pragma unroll
    for (int q = 0; q < 4; ++q)
#pragma unroll
        for (int m = 0; m < 4; ++m)
#pragma unroll
            for (int n = 0; n < 2; ++n)
#pragma unroll
                for (int r = 0; r < 4; ++r) acc[q][m][n][r] = 0.f;

    int NT = K >> 6;
    STAGE(Ag0, Abuf[0][0], 0);
    STAGE(Bg0, Bbuf[0][0], 0);
    STAGE(Ag1, Abuf[0][1], 0);
    STAGE(Bg1, Bbuf[0][1], 0);
    STAGE(Ag0, Abuf[1][0], 64);
    STAGE(Bg0, Bbuf[1][0], 64);
    STAGE(Ag1, Abuf[1][1], 64);
    STAGE(Bg1, Bbuf[1][1], 64);
    asm volatile("s_waitcnt vmcnt(8)" ::: "memory");
    __builtin_amdgcn_s_barrier();
#pragma unroll
    for (int m = 0; m < 4; ++m) { RD_A(0, 0, m, 0); RD_A(0, 0, m, 1); }
#pragma unroll
    for (int n = 0; n < 2; ++n) { RD_B(0, 0, n, 0); RD_B(0, 0, n, 1); }

    for (int t = 0; t < NT; ++t) {
        int cur = t & 1, nx = cur ^ 1;
        bool rd = (t + 1 < NT);
        bool st = (t + 2 < NT);
        int ks = (t + 2) << 6;

        // ---- PH0
#pragma unroll
        for (int m = 0; m < 4; ++m) { RD_A(cur, 1, m, 0); RD_A(cur, 1, m, 1); }
        asm volatile("s_waitcnt lgkmcnt(8)" ::: "memory");
        __builtin_amdgcn_sched_barrier(0);
        __builtin_amdgcn_s_setprio(1);
        QUAD(0, 0, 0);
        __builtin_amdgcn_s_setprio(0);

        // ---- PH1
#pragma unroll
        for (int n = 0; n < 2; ++n) { RD_B(cur, 1, n, 0); RD_B(cur, 1, n, 1); }
        asm volatile("s_waitcnt lgkmcnt(4)" ::: "memory");
        __builtin_amdgcn_sched_barrier(0);
        __builtin_amdgcn_s_setprio(1);
        QUAD(1, 1, 0);
        __builtin_amdgcn_s_setprio(0);

        // ---- PH2: single tile-boundary drain
        asm volatile("s_waitcnt lgkmcnt(0)" ::: "memory");
        asm volatile("s_waitcnt vmcnt(0)" ::: "memory");
        __builtin_amdgcn_s_barrier();
        if (st) {
            STAGE(Ag0, Abuf[cur][0], ks);
            STAGE(Bg0, Bbuf[cur][0], ks);
        }
        if (rd) {
#pragma unroll
            for (int n = 0; n < 2; ++n) { RD_B(nx, 0, n, 0); RD_B(nx, 0, n, 1); }
        }
        __builtin_amdgcn_s_setprio(1);
        QUAD(2, 0, 1);
        __builtin_amdgcn_s_setprio(0);

        // ---- PH3
        if (st) {
            STAGE(Ag1, Abuf[cur][1], ks);
            STAGE(Bg1, Bbuf[cur][1], ks);
        }
        if (rd) {
#pragma unroll
            for (int m = 0; m < 4; ++m) { RD_A(nx, 0, m, 0); RD_A(nx, 0, m, 1); }
        }
        __builtin_amdgcn_s_setprio(1);
        QUAD(3, 1, 1);
        __builtin_amdgcn_s_setprio(0);
    }

    // epilogue: block-uniform output select
    bool isQ = (bn < NQ);
    unsigned short* outp = isQ ? qkvp : gatep;
    int Nout = isQ ? 12288 : 4096;
    int colb0 = (isQ ? bn : bn - NQ) * 256;
#pragma unroll
    for (int q = 0; q < 4; ++q) {
        const int R_ = q & 1, C_ = q >> 1;
#pragma unroll
        for (int m = 0; m < 4; ++m) {
            int row0 = bm * 256 + R_ * 128 + wr * 64 + m * 16 + ((lane >> 4) * 4);
#pragma unroll
            for (int n = 0; n < 2; ++n) {
                int col = colb0 + C_ * 128 + wc * 32 + n * 16 + (lane & 15);
#pragma unroll
                for (int rg = 0; rg < 4; ++rg) {
                    float v = acc[q][m][n][rg];
                    float sig = 1.f / (1.f + __expf(-v));
                    float r = isQ ? v * sig : sig;
                    outp[(size_t)(row0 + rg) * Nout + col] = f2bf(r);
                }
            }
        }
    }
#undef STAGE
#undef RD_A
#undef RD_B
#undef QUAD
}

// ====== 128x128 pipelined out-GEMM (R10) ====================================
__global__ __launch_bounds__(256, 2) void gemm_out_kernel(const unsigned short* __restrict__ A,
                                                          const unsigned short* __restrict__ Bt,
                                                          float* __restrict__ Cout,
                                                          int N, int K, int NBN) {
    __shared__ unsigned short Abuf[2][2][4096];
    __shared__ unsigned short Bbuf[2][2][4096];

    int bid = blockIdx.x, nwg = gridDim.x;
    int wg = (bid & 7) * (nwg >> 3) + (bid >> 3);
    int bm = wg / NBN, bn = wg % NBN;
    int tid = threadIdx.x, lane = tid & 63, w = tid >> 6;
    int wr = w >> 1, wc = w & 1;

    int r0 = tid >> 3;
    int cbs = (tid & 7) << 4;
    int el0 = (cbs ^ ((r0 & 7) << 4)) >> 1;
    int r1 = 32 + r0;
    int el1 = (cbs ^ ((r1 & 7) << 4)) >> 1;
    int lo0 = tid * 16, lo1 = 4096 + tid * 16;

    const unsigned short* Ag0 = A + (size_t)(bm * 128) * K;
    const unsigned short* Ag1 = A + (size_t)(bm * 128 + 64) * K;
    const unsigned short* Bg0 = Bt + (size_t)(bn * 128) * K;
    const unsigned short* Bg1 = Bt + (size_t)(bn * 128 + 64) * K;

#define STAGE(src, dstHalf, k0)                                            \
    do {                                                                   \
        gl16((src) + (size_t)r0 * K + (k0) + el0, (char*)(dstHalf) + lo0); \
        gl16((src) + (size_t)r1 * K + (k0) + el1, (char*)(dstHalf) + lo1); \
    } while (0)

    int aRow = wr * 32 + (lane & 15);
    int bRow = wc * 32 + (lane & 15);
    int swz = (lane & 7) << 4;
    int cbb = (lane >> 4) << 4;

#define RD_A(slot, R, m, kk) \
    af[R][m][kk] = *(const bf16x8*)((const char*)Abuf[slot][R] + ((aRow + (m) * 16) << 7) + (((kk) * 64 + cbb) ^ swz))
#define RD_B(slot, Cq, n, kk) \
    bfr[Cq][n][kk] = *(const bf16x8*)((const char*)Bbuf[slot][Cq] + ((bRow + (n) * 16) << 7) + (((kk) * 64 + cbb) ^ swz))

#define QUAD(q, Rh, Cc)                                                       \
    do {                                                                      \
        _Pragma("unroll")                                                     \
        for (int m = 0; m < 2; ++m)                                           \
            _Pragma("unroll")                                                 \
            for (int n = 0; n < 2; ++n) {                                     \
                acc[q][m][n] = MFMA16(af[Rh][m][0], bfr[Cc][n][0], acc[q][m][n]); \
                acc[q][m][n] = MFMA16(af[Rh][m][1], bfr[Cc][n][1], acc[q][m][n]); \
            }                                                                 \
    } while (0)

    bf16x8 af[2][2][2];
    bf16x8 bfr[2][2][2];
    f32x4 acc[4][2][2];
#pragma unroll
    for (int q = 0; q < 4; ++q)
#pragma unroll
        for (int m = 0; m < 2; ++m)
#pragma unroll
            for (int n = 0; n < 2; ++n)
#pragma unroll
                for (int r = 0; r < 4; ++r) acc[q][m][n][r] = 0.f;

    int NT = K >> 6;
    STAGE(Ag0, Abuf[0][0], 0);
    STAGE(Bg0, Bbuf[0][0], 0);
    STAGE(Ag1, Abuf[0][1], 0);
    STAGE(Bg1, Bbuf[0][1], 0);
    STAGE(Ag0, Abuf[1][0], 64);
    STAGE(Bg0, Bbuf[1][0], 64);
    STAGE(Ag1, Abuf[1][1], 64);
    STAGE(Bg1, Bbuf[1][1], 64);
    asm volatile("s_waitcnt vmcnt(8)" ::: "memory");
    __builtin_amdgcn_s_barrier();
#pragma unroll
    for (int m = 0; m < 2; ++m) { RD_A(0, 0, m, 0); RD_A(0, 0, m, 1); }
#pragma unroll
    for (int n = 0; n < 2; ++n) { RD_B(0, 0, n, 0); RD_B(0, 0, n, 1); }

    for (int t = 0; t < NT; ++t) {
        int cur = t & 1, nx = cur ^ 1;
        bool rd = (t + 1 < NT);
        bool st = (t + 2 < NT);
        int ks = (t + 2) << 6;

        // ---- PH0
#pragma unroll
        for (int m = 0; m < 2; ++m) { RD_A(cur, 1, m, 0); RD_A(cur, 1, m, 1); }
        asm volatile("s_waitcnt lgkmcnt(4)" ::: "memory");
        __builtin_amdgcn_sched_barrier(0);
        __builtin_amdgcn_s_setprio(1);
        QUAD(0, 0, 0);
        __builtin_amdgcn_s_setprio(0);

        // ---- PH1
#pragma unroll
        for (int n = 0; n < 2; ++n) { RD_B(cur, 1, n, 0); RD_B(cur, 1, n, 1); }
        asm volatile("s_waitcnt lgkmcnt(4)" ::: "memory");
        __builtin_amdgcn_sched_barrier(0);
        __builtin_amdgcn_s_setprio(1);
        QUAD(1, 1, 0);
        __builtin_amdgcn_s_setprio(0);

        // ---- PH2: single tile-boundary drain
        asm volatile("s_waitcnt lgkmcnt(0)" ::: "memory");
        asm volatile("s_waitcnt vmcnt(0)" ::: "memory");
        __builtin_amdgcn_s_barrier();
        if (st) {
            STAGE(Ag0, Abuf[cur][0], ks);
            STAGE(Bg0, Bbuf[cur][0], ks);
        }
        if (rd) {
#pragma unroll
            for (int n = 0; n < 2; ++n) { RD_B(nx, 0, n, 0); RD_B(nx, 0, n, 1); }
        }
        __builtin_amdgcn_s_setprio(1);
        QUAD(2, 0, 1);
        __builtin_amdgcn_s_setprio(0);

        // ---- PH3
        if (st) {
            STAGE(Ag1, Abuf[cur][1], ks);
            STAGE(Bg1, Bbuf[cur][1], ks);
        }
        if (rd) {
#pragma unroll
            for (int m = 0; m < 2; ++m) { RD_A(nx, 0, m, 0); RD_A(nx, 0, m, 1); }
        }
        __builtin_amdgcn_s_setprio(1);
        QUAD(3, 1, 1);
        __builtin_amdgcn_s_setprio(0);
    }

    // epilogue (f32 out)
#pragma unroll
    for (int q = 0; q < 4; ++q) {
        const int R_ = q & 1, C_ = q >> 1;
#pragma unroll
        for (int m = 0; m < 2; ++m) {
            int row0 = bm * 128 + R_ * 64 + wr * 32 + m * 16 + ((lane >> 4) * 4);
#pragma unroll
            for (int n = 0; n < 2; ++n) {
                int col = bn * 128 + C_ * 64 + wc * 32 + n * 16 + (lane & 15);
#pragma unroll
                for (int rg = 0; rg < 4; ++rg)
                    Cout[(size_t)(row0 + rg) * N + col] = acc[q][m][n][rg];
            }
        }
    }
#undef STAGE
#undef RD_A
#undef RD_B
#undef QUAD
}

// ---------- qkv -> kts (scaled, transposed), vt (transposed); 64x64 tiles ----------
__global__ __launch_bounds__(256) void kv_transpose_kernel(const unsigned short* __restrict__ qkv,
                                                           const float* __restrict__ slopes,
                                                           unsigned short* __restrict__ kts,
                                                           unsigned short* __restrict__ vt) {
    __shared__ unsigned short tk[64][66];
    __shared__ unsigned short tv[64][66];
    int n0 = blockIdx.x * 64, d0 = blockIdx.y * 64, h = blockIdx.z;
    float s = slopes[h];
    int tid = threadIdx.x;
    int tr = tid >> 4;
    int tc4 = (tid & 15) * 4;
#pragma unroll
    for (int it = 0; it < 4; ++it) {
        int r = it * 16 + tr;
        int n = n0 + r;
        size_t rowb = (size_t)n * 12288 + h * 384;
        float sc = __expf(-s * (float)(255 - (n & 255)));
        ushort4 k4 = *(const ushort4*)&qkv[rowb + 128 + d0 + tc4];
        ushort4 v4 = *(const ushort4*)&qkv[rowb + 256 + d0 + tc4];
        tk[r][tc4 + 0] = f2bf(bf2f(k4.x) * sc);
        tk[r][tc4 + 1] = f2bf(bf2f(k4.y) * sc);
        tk[r][tc4 + 2] = f2bf(bf2f(k4.z) * sc);
        tk[r][tc4 + 3] = f2bf(bf2f(k4.w) * sc);
        tv[r][tc4 + 0] = v4.x;
        tv[r][tc4 + 1] = v4.y;
        tv[r][tc4 + 2] = v4.z;
        tv[r][tc4 + 3] = v4.w;
    }
    __syncthreads();
#pragma unroll
    for (int it = 0; it < 4; ++it) {
        int c = it * 16 + tr;
        ushort4 ok, ov;
        ok.x = tk[tc4 + 0][c]; ok.y = tk[tc4 + 1][c];
        ok.z = tk[tc4 + 2][c]; ok.w = tk[tc4 + 3][c];
        ov.x = tv[tc4 + 0][c]; ov.y = tv[tc4 + 1][c];
        ov.z = tv[tc4 + 2][c]; ov.w = tv[tc4 + 3][c];
        size_t ob = (size_t)(h * 128 + d0 + c) * 4096 + n0 + tc4;
        *(ushort4*)&kts[ob] = ok;
        *(ushort4*)&vt[ob] = ov;
    }
}

// ---------- per-block KV outer product ----------
__global__ __launch_bounds__(256) void kv_outer_kernel(const unsigned short* __restrict__ kts,
                                                       const unsigned short* __restrict__ vt,
                                                       float* __restrict__ U) {
    __shared__ unsigned short Kc[128 * 64];
    __shared__ unsigned short Vc[128 * 64];
    int blk = blockIdx.x;
    int h = blk & 31, t = blk >> 5;
    int tid = threadIdx.x, lane = tid & 63, w = tid >> 6;

    f32x4 acc[2][8];
#pragma unroll
    for (int m = 0; m < 2; ++m)
#pragma unroll
        for (int n = 0; n < 8; ++n)
#pragma unroll
            for (int r = 0; r < 4; ++r) acc[m][n][r] = 0.f;

    for (int ks = 0; ks < 4; ++ks) {
        __syncthreads();
#pragma unroll
        for (int it = 0; it < 4; ++it) {
            int slot = it * 256 + tid;
            int o = slot * 16;
            int r = o >> 7;
            int cb = o & 127;
            int scb = cb ^ ((r & 7) << 4);
            size_t j = (size_t)t * 256 + ks * 64 + (scb >> 1);
            gl16(kts + (size_t)(h * 128 + r) * 4096 + j, (char*)Kc + o);
            gl16(vt + (size_t)(h * 128 + r) * 4096 + j, (char*)Vc + o);
        }
        __syncthreads();
#pragma unroll
        for (int kk = 0; kk < 2; ++kk) {
            int kb = kk * 64 + ((lane >> 4) * 16);
            bf16x8 vf[2], kf[8];
#pragma unroll
            for (int m = 0; m < 2; ++m) {
                int e = w * 32 + m * 16 + (lane & 15);
                vf[m] = *(const bf16x8*)((const char*)Vc + (e << 7) + (kb ^ ((e & 7) << 4)));
            }
#pragma unroll
            for (int n = 0; n < 8; ++n) {
                int d = n * 16 + (lane & 15);
                kf[n] = *(const bf16x8*)((const char*)Kc + (d << 7) + (kb ^ ((d & 7) << 4)));
            }
#pragma unroll
            for (int m = 0; m < 2; ++m)
#pragma unroll
                for (int n = 0; n < 8; ++n)
                    acc[m][n] = MFMA16(vf[m], kf[n], acc[m][n]);
        }
    }
    size_t base = (size_t)(h * 16 + t) * 16384;
#pragma unroll
    for (int m = 0; m < 2; ++m)
#pragma unroll
        for (int n = 0; n < 8; ++n)
#pragma unroll
            for (int r = 0; r < 4; ++r) {
                int e = w * 32 + m * 16 + ((lane >> 4) * 4) + r;
                int d = n * 16 + (lane & 15);
                U[base + (size_t)e * 128 + d] = acc[m][n][r];
            }
}

// ---------- parallel scan: 32 heads x 16 chunks of 1024 ----------
__global__ __launch_bounds__(256) void kv_scan_kernel(const float* __restrict__ kv_cache,
                                                      const float* __restrict__ U,
                                                      const float* __restrict__ slopes,
                                                      unsigned short* __restrict__ Wb) {
    __shared__ float Tt[8][132];
    int h = blockIdx.x >> 4;
    int c = blockIdx.x & 15;
    int c0 = c * 1024, e0 = c * 8;
    int tid = threadIdx.x;
    float s = slopes[h];
    float bd = __expf(-s * 256.f);
    size_t hb = (size_t)h * 16384;
#pragma unroll
    for (int it = 0; it < 4; ++it) {
        int d = it * 32 + (tid >> 3);
        Tt[tid & 7][d] = kv_cache[hb + (size_t)d * 128 + e0 + (tid & 7)];
    }
    __syncthreads();
    float wst[4];
#pragma unroll
    for (int i = 0; i < 4; ++i) {
        int local = i * 256 + tid;
        wst[i] = Tt[local >> 7][local & 127];
    }
    for (int t = 0; t < 16; ++t) {
        size_t base = (size_t)(h * 16 + t) * 16384 + c0;
#pragma unroll
        for (int i = 0; i < 4; ++i) {
            int idx = i * 256 + tid;
            Wb[base + idx] = f2bf(wst[i]);
            wst[i] = bd * wst[i] + U[base + idx];
        }
    }
}

// ---------- fused attention block kernel: QBLK=128, 80KB LDS, 2 WG/CU ----------
__global__ __launch_bounds__(256, 2) void attn_out_kernel(const unsigned short* __restrict__ qkv,
                                                          const unsigned short* __restrict__ vt,
                                                          const unsigned short* __restrict__ Wb,
                                                          const float* __restrict__ slopes,
                                                          unsigned short* __restrict__ attn) {
    __shared__ unsigned short lds[40960];  // 80 KB
    unsigned short* Qs = lds;
    unsigned short* Ps = lds + 16384;
    unsigned short* KW = lds + 24576;
    unsigned short* Ks = KW;
    unsigned short* Vs = KW + 8192;

    int blk = blockIdx.x;
    int h = blk & 31, tq = blk >> 5;
    int t = tq >> 1, qh = tq & 1;
    float s = slopes[h];
    int tid = threadIdx.x, lane = tid & 63, w = tid >> 6;
    int rowbase = t * 256 + qh * 128;

#pragma unroll
    for (int it = 0; it < 8; ++it) {
        int o = (it * 256 + tid) * 16;
        int r = o >> 8, cb = o & 255, scb = cb ^ ((r & 7) << 4);
        gl16(qkv + (size_t)(rowbase + r) * 12288 + h * 384 + (scb >> 1), (char*)Qs + o);
    }
#pragma unroll
    for (int it = 0; it < 8; ++it) {
        int o = (it * 256 + tid) * 16;
        int e = o >> 8, cb = o & 255, scb = cb ^ ((e & 7) << 4);
        gl16(Wb + (size_t)((h * 16 + t) * 128 + e) * 128 + (scb >> 1), (char*)KW + o);
    }
    __syncthreads();

    f32x4 acc[2][8];
#pragma unroll
    for (int m = 0; m < 2; ++m)
#pragma unroll
        for (int n = 0; n < 8; ++n)
#pragma unroll
            for (int r = 0; r < 4; ++r) acc[m][n][r] = 0.f;

#pragma unroll
    for (int kk = 0; kk < 4; ++kk) {
        int kb = kk * 64 + ((lane >> 4) * 16);
        bf16x8 qf[2], wf[8];
#pragma unroll
        for (int m = 0; m < 2; ++m) {
            int r = w * 32 + m * 16 + (lane & 15);
            qf[m] = *(const bf16x8*)((const char*)Qs + (r << 8) + (kb ^ ((r & 7) << 4)));
        }
#pragma unroll
        for (int n = 0; n < 8; ++n) {
            int e = n * 16 + (lane & 15);
            wf[n] = *(const bf16x8*)((const char*)KW + (e << 8) + (kb ^ ((e & 7) << 4)));
        }
#pragma unroll
        for (int m = 0; m < 2; ++m)
#pragma unroll
            for (int n = 0; n < 8; ++n)
                acc[m][n] = MFMA16(qf[m], wf[n], acc[m][n]);
    }
#pragma unroll
    for (int m = 0; m < 2; ++m)
#pragma unroll
        for (int rg = 0; rg < 4; ++rg) {
            int i = qh * 128 + w * 32 + m * 16 + ((lane >> 4) * 4) + rg;
            float qd = __expf(-s * (float)(i + 1));
#pragma unroll
            for (int n = 0; n < 8; ++n) acc[m][n][rg] *= qd;
        }

    int jbmax = ((qh << 2) + w) >> 1;
    for (int jb = 0; jb < 4; ++jb) {
        __syncthreads();
#pragma unroll
        for (int it = 0; it < 4; ++it) {
            int o = (it * 256 + tid) * 16;
            int r = o >> 8, cb = o & 255, scb = cb ^ ((r & 7) << 4);
            gl16(qkv + (size_t)(t * 256 + jb * 64 + r) * 12288 + h * 384 + 128 + (scb >> 1),
                 (char*)Ks + o);
        }
#pragma unroll
        for (int it = 0; it < 4; ++it) {
            int o = (it * 256 + tid) * 16;
            int e = o >> 7, cb = o & 127, scb = cb ^ ((e & 7) << 4);
            gl16(vt + (size_t)(h * 128 + e) * 4096 + t * 256 + jb * 64 + (scb >> 1),
                 (char*)Vs + o);
        }
        __syncthreads();

        if (jb <= jbmax) {
            f32x4 sc[2][4];
#pragma unroll
            for (int m = 0; m < 2; ++m)
#pragma unroll
                for (int n = 0; n < 4; ++n)
#pragma unroll
                    for (int r = 0; r < 4; ++r) sc[m][n][r] = 0.f;
#pragma unroll
            for (int kk = 0; kk < 4; ++kk) {
                int kb = kk * 64 + ((lane >> 4) * 16);
                bf16x8 qf[2], kf[4];
#pragma unroll
                for (int m = 0; m < 2; ++m) {
                    int r = w * 32 + m * 16 + (lane & 15);
                    qf[m] = *(const bf16x8*)((const char*)Qs + (r << 8) + (kb ^ ((r & 7) << 4)));
                }
#pragma unroll
                for (int n = 0; n < 4; ++n) {
                    int r = n * 16 + (lane & 15);
                    kf[n] = *(const bf16x8*)((const char*)Ks + (r << 8) + (kb ^ ((r & 7) << 4)));
                }
#pragma unroll
                for (int m = 0; m < 2; ++m)
#pragma unroll
                    for (int n = 0; n < 4; ++n)
                        sc[m][n] = MFMA16(qf[m], kf[n], sc[m][n]);
            }
            unsigned short* Pw = Ps + w * 2048;
#pragma unroll
            for (int m = 0; m < 2; ++m)
#pragma unroll
                for (int n = 0; n < 4; ++n)
#pragma unroll
                    for (int rg = 0; rg < 4; ++rg) {
                        int il = m * 16 + ((lane >> 4) * 4) + rg;
                        int i = qh * 128 + w * 32 + il;
                        int jl = n * 16 + (lane & 15);
                        int j = jb * 64 + jl;
                        float v = 0.f;
                        if (i >= j) v = sc[m][n][rg] * __expf(-s * (float)(i - j));
                        int cb2 = (jl * 2) ^ ((il & 7) << 4);
                        *(unsigned short*)((char*)Pw + (il << 7) + cb2) = f2bf(v);
                    }
            asm volatile("s_waitcnt lgkmcnt(0)" ::: "memory");
#pragma unroll
            for (int kk = 0; kk < 2; ++kk) {
                int kb = kk * 64 + ((lane >> 4) * 16);
                bf16x8 pf[2], vf[8];
#pragma unroll
                for (int m = 0; m < 2; ++m) {
                    int il = m * 16 + (lane & 15);
                    pf[m] = *(const bf16x8*)((const char*)Pw + (il << 7) + (kb ^ ((il & 7) << 4)));
                }
#pragma unroll
                for (int n = 0; n < 8; ++n) {
                    int e = n * 16 + (lane & 15);
                    vf[n] = *(const bf16x8*)((const char*)Vs + (e << 7) + (kb ^ ((e & 7) << 4)));
                }
#pragma unroll
                for (int m = 0; m < 2; ++m)
#pragma unroll
                    for (int n = 0; n < 8; ++n)
                        acc[m][n] = MFMA16(pf[m], vf[n], acc[m][n]);
            }
        }
    }

#pragma unroll
    for (int m = 0; m < 2; ++m)
#pragma unroll
        for (int n = 0; n < 8; ++n)
#pragma unroll
            for (int rg = 0; rg < 4; ++rg) {
                int i = qh * 128 + w * 32 + m * 16 + ((lane >> 4) * 4) + rg;
                int col = h * 128 + n * 16 + (lane & 15);
                attn[(size_t)(t * 256 + i) * 4096 + col] = f2bf(acc[m][n][rg]);
            }
}

// ---------- RMSNorm + sigmoid-gate multiply ----------
__global__ __launch_bounds__(256) void rms_gate_kernel(const unsigned short* __restrict__ attn,
                                                       const unsigned short* __restrict__ gate,
                                                       const float* __restrict__ nw,
                                                       unsigned short* __restrict__ gated) {
    int row = blockIdx.x, tid = threadIdx.x;
    int lane = tid & 63, w = tid >> 6;
    const unsigned short* ar = attn + (size_t)row * 4096 + tid * 16;
    u16x8 a0 = *(const u16x8*)ar;
    u16x8 a1 = *(const u16x8*)(ar + 8);
    float v[16];
    float ss = 0.f;
#pragma unroll
    for (int j = 0; j < 8; ++j) { v[j] = bf2f(a0[j]); v[8 + j] = bf2f(a1[j]); }
#pragma unroll
    for (int j = 0; j < 16; ++j) ss += v[j] * v[j];
#pragma unroll
    for (int o = 32; o > 0; o >>= 1) ss += __shfl_xor(ss, o);
    __shared__ float red[4];
    if (lane == 0) red[w] = ss;
    __syncthreads();
    float tot = red[0] + red[1] + red[2] + red[3];
    float rs = rsqrtf(tot * (1.f / 4096.f) + 1e-5f);
    const unsigned short* gr = gate + (size_t)row * 4096 + tid * 16;
    u16x8 g0 = *(const u16x8*)gr;
    u16x8 g1 = *(const u16x8*)(gr + 8);
    const float* nwp = nw + tid * 16;
    u16x8 o0, o1;
#pragma unroll
    for (int j = 0; j < 8; ++j) {
        o0[j] = f2bf(v[j] * rs * nwp[j] * bf2f(g0[j]));
        o1[j] = f2bf(v[8 + j] * rs * nwp[8 + j] * bf2f(g1[j]));
    }
    unsigned short* gp = gated + (size_t)row * 4096 + tid * 16;
    *(u16x8*)gp = o0;
    *(u16x8*)(gp + 8) = o1;
}

// ---------- launcher ----------
extern "C" void kernel_launch(void* const* d_in, const int* in_sizes, int n_in,
                              void* d_out, int out_size, void* d_ws, size_t ws_size,
                              hipStream_t stream) {
    const float* hs       = (const float*)d_in[0];
    const float* w_qkv    = (const float*)d_in[1];
    const float* w_gate   = (const float*)d_in[2];
    const float* w_out    = (const float*)d_in[3];
    const float* nw       = (const float*)d_in[4];
    const float* slopes   = (const float*)d_in[5];
    const float* kv_cache = (const float*)d_in[6];
    float* out = (float*)d_out;
    char* ws = (char*)d_ws;

    unsigned short* hsb  = (unsigned short*)(ws + 0);
    unsigned short* wqt  = (unsigned short*)(ws + 16777216);
    unsigned short* wgt  = (unsigned short*)(ws + 67108864);
    unsigned short* wot  = (unsigned short*)(ws + 83886080);
    unsigned short* qkv  = (unsigned short*)(ws + 100663296);
    unsigned short* gate = (unsigned short*)(ws + 201326592);
    unsigned short* kts  = (unsigned short*)(ws + 234881024);
    unsigned short* vt   = (unsigned short*)(ws + 268435456);
    float*          U    = (float*)(ws + 301989888);
    unsigned short* Wb   = (unsigned short*)(ws + 335544320);
    unsigned short* attn  = wqt;  // reuse
    unsigned short* gated = qkv;  // reuse

    prep_kernel<<<14336, 256, 0, stream>>>(hs, w_qkv, w_gate, w_out, hsb, wqt, wgt, wot);
    gemm_qkvgate_kernel<<<1024, 512, 0, stream>>>(hsb, wqt, qkv, gate, 2048, 64, 48);
    {
        dim3 g(64, 2, 32);
        kv_transpose_kernel<<<g, 256, 0, stream>>>(qkv, slopes, kts, vt);
    }
    kv_outer_kernel<<<512, 256, 0, stream>>>(kts, vt, U);
    kv_scan_kernel<<<512, 256, 0, stream>>>(kv_cache, U, slopes, Wb);
    attn_out_kernel<<<1024, 256, 0, stream>>>(qkv, vt, Wb, slopes, attn);
    rms_gate_kernel<<<4096, 256, 0, stream>>>(attn, gate, nw, gated);
    gemm_out_kernel<<<512, 256, 0, stream>>>(gated, wot, out, 2048, 4096, 16);
}

// Round 16
// 462.609 us; speedup vs baseline: 1.0984x; 1.0101x over previous
//
#include <hip/hip_runtime.h>
#include <stdint.h>

// ---------- types & helpers ----------
typedef __bf16 bf16x8 __attribute__((ext_vector_type(8)));
typedef float  f32x4  __attribute__((ext_vector_type(4)));
typedef unsigned short u16x8 __attribute__((ext_vector_type(8)));

__device__ __forceinline__ unsigned short f2bf(float f) {
    union { float f; uint32_t u; } x; x.f = f;
    uint32_t r = (x.u + 0x7FFFu + ((x.u >> 16) & 1u)) >> 16;
    return (unsigned short)r;
}
__device__ __forceinline__ float bf2f(unsigned short b) {
    union { uint32_t u; float f; } x; x.u = ((uint32_t)b) << 16;
    return x.f;
}

// global -> LDS direct (16B per lane). LDS dest: wave-uniform base + lane*16.
__device__ __forceinline__ void gl16(const void* g, void* l) {
    __builtin_amdgcn_global_load_lds(
        (const __attribute__((address_space(1))) void*)g,
        (__attribute__((address_space(3))) void*)(uint32_t)(uintptr_t)l,
        16, 0, 0);
}

#define MFMA16(a, b, c) __builtin_amdgcn_mfma_f32_16x16x32_bf16((a), (b), (c), 0, 0, 0)

// ---------- merged prep: hs f32->bf16 + 3 weight transposes ----------
__global__ __launch_bounds__(256) void prep_kernel(const float* __restrict__ hs,
                                                   const float* __restrict__ w_qkv,
                                                   const float* __restrict__ w_gate,
                                                   const float* __restrict__ w_out,
                                                   unsigned short* __restrict__ hsb,
                                                   unsigned short* __restrict__ wqt,
                                                   unsigned short* __restrict__ wgt,
                                                   unsigned short* __restrict__ wot) {
    __shared__ float tile[64][65];
    int b = blockIdx.x, tid = threadIdx.x;
    if (b >= 10240) {
        int i = (b - 10240) * 256 + tid;
        float4 a = ((const float4*)hs)[2 * i];
        float4 c = ((const float4*)hs)[2 * i + 1];
        u16x8 o;
        o[0] = f2bf(a.x); o[1] = f2bf(a.y); o[2] = f2bf(a.z); o[3] = f2bf(a.w);
        o[4] = f2bf(c.x); o[5] = f2bf(c.y); o[6] = f2bf(c.z); o[7] = f2bf(c.w);
        ((u16x8*)hsb)[i] = o;
        return;
    }
    const float* in; unsigned short* out; int R, C, bx, by;
    if (b < 6144)      { in = w_qkv;  out = wqt; R = 2048; C = 12288; bx = b % 192; by = b / 192; }
    else if (b < 8192) { int bb = b - 6144; in = w_gate; out = wgt; R = 2048; C = 4096; bx = bb % 64; by = bb / 64; }
    else               { int bb = b - 8192; in = w_out;  out = wot; R = 4096; C = 2048; bx = bb % 32; by = bb / 32; }
    int c0 = bx * 64, r0 = by * 64;
    int tr = tid >> 4;
    int tc4 = (tid & 15) * 4;
#pragma unroll
    for (int it = 0; it < 4; ++it) {
        int r = it * 16 + tr;
        float4 v = *(const float4*)&in[(size_t)(r0 + r) * C + c0 + tc4];
        tile[r][tc4] = v.x; tile[r][tc4 + 1] = v.y;
        tile[r][tc4 + 2] = v.z; tile[r][tc4 + 3] = v.w;
    }
    __syncthreads();
#pragma unroll
    for (int it = 0; it < 4; ++it) {
        int c = it * 16 + tr;
        ushort4 o;
        o.x = f2bf(tile[tc4][c]);
        o.y = f2bf(tile[tc4 + 1][c]);
        o.z = f2bf(tile[tc4 + 2][c]);
        o.w = f2bf(tile[tc4 + 3][c]);
        *(ushort4*)&out[(size_t)(c0 + c) * R + r0 + tc4] = o;
    }
}

// ====== 256x256 register-pipelined 4-phase GEMM, fused qkv+gate (R10) =======
__global__ __launch_bounds__(512, 2) void gemm_qkvgate_kernel(const unsigned short* __restrict__ A,
                                                              const unsigned short* __restrict__ Bt,
                                                              unsigned short* __restrict__ qkvp,
                                                              unsigned short* __restrict__ gatep,
                                                              int K, int NBN, int NQ) {
    __shared__ unsigned short Abuf[2][2][8192];
    __shared__ unsigned short Bbuf[2][2][8192];

    int bid = blockIdx.x;
    int xcd = bid & 7, kw = bid >> 3;
    int bm = (xcd & 3) * 4 + (kw & 3);
    int bn = (xcd >> 2) * (NBN >> 1) + (kw >> 2);
    int tid = threadIdx.x, lane = tid & 63, w = tid >> 6;
    int wr = w >> 2, wc = w & 3;

    int r0 = tid >> 3;
    int cbs = (tid & 7) << 4;
    int el0 = (cbs ^ ((r0 & 7) << 4)) >> 1;
    int r1 = 64 + r0;
    int el1 = (cbs ^ ((r1 & 7) << 4)) >> 1;
    int lo0 = tid * 16, lo1 = 8192 + tid * 16;

    const unsigned short* Ag0 = A + (size_t)(bm * 256) * K;
    const unsigned short* Ag1 = A + (size_t)(bm * 256 + 128) * K;
    const unsigned short* Bg0 = Bt + (size_t)(bn * 256) * K;
    const unsigned short* Bg1 = Bt + (size_t)(bn * 256 + 128) * K;

#define STAGE(src, dstHalf, k0)                                            \
    do {                                                                   \
        gl16((src) + (size_t)r0 * K + (k0) + el0, (char*)(dstHalf) + lo0); \
        gl16((src) + (size_t)r1 * K + (k0) + el1, (char*)(dstHalf) + lo1); \
    } while (0)

    int aRow = wr * 64 + (lane & 15);
    int bRow = wc * 32 + (lane & 15);
    int swz = (lane & 7) << 4;
    int cbb = (lane >> 4) << 4;

#define RD_A(slot, R, m, kk) \
    af[R][m][kk] = *(const bf16x8*)((const char*)Abuf[slot][R] + ((aRow + (m) * 16) << 7) + (((kk) * 64 + cbb) ^ swz))
#define RD_B(slot, Cq, n, kk) \
    bfr[Cq][n][kk] = *(const bf16x8*)((const char*)Bbuf[slot][Cq] + ((bRow + (n) * 16) << 7) + (((kk) * 64 + cbb) ^ swz))

#define QUAD(q, Rh, Cc)                                                       \
    do {                                                                      \
        _Pragma("unroll")                                                     \
        for (int m = 0; m < 4; ++m)                                           \
            _Pragma("unroll")                                                 \
            for (int n = 0; n < 2; ++n) {                                     \
                acc[q][m][n] = MFMA16(af[Rh][m][0], bfr[Cc][n][0], acc[q][m][n]); \
                acc[q][m][n] = MFMA16(af[Rh][m][1], bfr[Cc][n][1], acc[q][m][n]); \
            }                                                                 \
    } while (0)

    bf16x8 af[2][4][2];
    bf16x8 bfr[2][2][2];
    f32x4 acc[4][4][2];
#pragma unroll
    for (int q = 0; q < 4; ++q)
#pragma unroll
        for (int m = 0; m < 4; ++m)
#pragma unroll
            for (int n = 0; n < 2; ++n)
#pragma unroll
                for (int r = 0; r < 4; ++r) acc[q][m][n][r] = 0.f;

    int NT = K >> 6;
    STAGE(Ag0, Abuf[0][0], 0);
    STAGE(Bg0, Bbuf[0][0], 0);
    STAGE(Ag1, Abuf[0][1], 0);
    STAGE(Bg1, Bbuf[0][1], 0);
    STAGE(Ag0, Abuf[1][0], 64);
    STAGE(Bg0, Bbuf[1][0], 64);
    STAGE(Ag1, Abuf[1][1], 64);
    STAGE(Bg1, Bbuf[1][1], 64);
    asm volatile("s_waitcnt vmcnt(8)" ::: "memory");
    __builtin_amdgcn_s_barrier();
#pragma unroll
    for (int m = 0; m < 4; ++m) { RD_A(0, 0, m, 0); RD_A(0, 0, m, 1); }
#pragma unroll
    for (int n = 0; n < 2; ++n) { RD_B(0, 0, n, 0); RD_B(0, 0, n, 1); }

    for (int t = 0; t < NT; ++t) {
        int cur = t & 1, nx = cur ^ 1;
        bool rd = (t + 1 < NT);
        bool st = (t + 2 < NT);
        int ks = (t + 2) << 6;

        // ---- PH0
#pragma unroll
        for (int m = 0; m < 4; ++m) { RD_A(cur, 1, m, 0); RD_A(cur, 1, m, 1); }
        asm volatile("s_waitcnt lgkmcnt(8)" ::: "memory");
        __builtin_amdgcn_sched_barrier(0);
        __builtin_amdgcn_s_setprio(1);
        QUAD(0, 0, 0);
        __builtin_amdgcn_s_setprio(0);

        // ---- PH1
#pragma unroll
        for (int n = 0; n < 2; ++n) { RD_B(cur, 1, n, 0); RD_B(cur, 1, n, 1); }
        asm volatile("s_waitcnt lgkmcnt(4)" ::: "memory");
        __builtin_amdgcn_sched_barrier(0);
        __builtin_amdgcn_s_setprio(1);
        QUAD(1, 1, 0);
        __builtin_amdgcn_s_setprio(0);

        // ---- PH2: single tile-boundary drain
        asm volatile("s_waitcnt lgkmcnt(0)" ::: "memory");
        asm volatile("s_waitcnt vmcnt(0)" ::: "memory");
        __builtin_amdgcn_s_barrier();
        if (st) {
            STAGE(Ag0, Abuf[cur][0], ks);
            STAGE(Bg0, Bbuf[cur][0], ks);
        }
        if (rd) {
#pragma unroll
            for (int n = 0; n < 2; ++n) { RD_B(nx, 0, n, 0); RD_B(nx, 0, n, 1); }
        }
        __builtin_amdgcn_s_setprio(1);
        QUAD(2, 0, 1);
        __builtin_amdgcn_s_setprio(0);

        // ---- PH3
        if (st) {
            STAGE(Ag1, Abuf[cur][1], ks);
            STAGE(Bg1, Bbuf[cur][1], ks);
        }
        if (rd) {
#pragma unroll
            for (int m = 0; m < 4; ++m) { RD_A(nx, 0, m, 0); RD_A(nx, 0, m, 1); }
        }
        __builtin_amdgcn_s_setprio(1);
        QUAD(3, 1, 1);
        __builtin_amdgcn_s_setprio(0);
    }

    // epilogue: block-uniform output select
    bool isQ = (bn < NQ);
    unsigned short* outp = isQ ? qkvp : gatep;
    int Nout = isQ ? 12288 : 4096;
    int colb0 = (isQ ? bn : bn - NQ) * 256;
#pragma unroll
    for (int q = 0; q < 4; ++q) {
        const int R_ = q & 1, C_ = q >> 1;
#pragma unroll
        for (int m = 0; m < 4; ++m) {
            int row0 = bm * 256 + R_ * 128 + wr * 64 + m * 16 + ((lane >> 4) * 4);
#pragma unroll
            for (int n = 0; n < 2; ++n) {
                int col = colb0 + C_ * 128 + wc * 32 + n * 16 + (lane & 15);
#pragma unroll
                for (int rg = 0; rg < 4; ++rg) {
                    float v = acc[q][m][n][rg];
                    float sig = 1.f / (1.f + __expf(-v));
                    float r = isQ ? v * sig : sig;
                    outp[(size_t)(row0 + rg) * Nout + col] = f2bf(r);
                }
            }
        }
    }
#undef STAGE
#undef RD_A
#undef RD_B
#undef QUAD
}

// ====== 128x128 pipelined out-GEMM (R10) ====================================
__global__ __launch_bounds__(256, 2) void gemm_out_kernel(const unsigned short* __restrict__ A,
                                                          const unsigned short* __restrict__ Bt,
                                                          float* __restrict__ Cout,
                                                          int N, int K, int NBN) {
    __shared__ unsigned short Abuf[2][2][4096];
    __shared__ unsigned short Bbuf[2][2][4096];

    int bid = blockIdx.x, nwg = gridDim.x;
    int wg = (bid & 7) * (nwg >> 3) + (bid >> 3);
    int bm = wg / NBN, bn = wg % NBN;
    int tid = threadIdx.x, lane = tid & 63, w = tid >> 6;
    int wr = w >> 1, wc = w & 1;

    int r0 = tid >> 3;
    int cbs = (tid & 7) << 4;
    int el0 = (cbs ^ ((r0 & 7) << 4)) >> 1;
    int r1 = 32 + r0;
    int el1 = (cbs ^ ((r1 & 7) << 4)) >> 1;
    int lo0 = tid * 16, lo1 = 4096 + tid * 16;

    const unsigned short* Ag0 = A + (size_t)(bm * 128) * K;
    const unsigned short* Ag1 = A + (size_t)(bm * 128 + 64) * K;
    const unsigned short* Bg0 = Bt + (size_t)(bn * 128) * K;
    const unsigned short* Bg1 = Bt + (size_t)(bn * 128 + 64) * K;

#define STAGE(src, dstHalf, k0)                                            \
    do {                                                                   \
        gl16((src) + (size_t)r0 * K + (k0) + el0, (char*)(dstHalf) + lo0); \
        gl16((src) + (size_t)r1 * K + (k0) + el1, (char*)(dstHalf) + lo1); \
    } while (0)

    int aRow = wr * 32 + (lane & 15);
    int bRow = wc * 32 + (lane & 15);
    int swz = (lane & 7) << 4;
    int cbb = (lane >> 4) << 4;

#define RD_A(slot, R, m, kk) \
    af[R][m][kk] = *(const bf16x8*)((const char*)Abuf[slot][R] + ((aRow + (m) * 16) << 7) + (((kk) * 64 + cbb) ^ swz))
#define RD_B(slot, Cq, n, kk) \
    bfr[Cq][n][kk] = *(const bf16x8*)((const char*)Bbuf[slot][Cq] + ((bRow + (n) * 16) << 7) + (((kk) * 64 + cbb) ^ swz))

#define QUAD(q, Rh, Cc)                                                       \
    do {                                                                      \
        _Pragma("unroll")                                                     \
        for (int m = 0; m < 2; ++m)                                           \
            _Pragma("unroll")                                                 \
            for (int n = 0; n < 2; ++n) {                                     \
                acc[q][m][n] = MFMA16(af[Rh][m][0], bfr[Cc][n][0], acc[q][m][n]); \
                acc[q][m][n] = MFMA16(af[Rh][m][1], bfr[Cc][n][1], acc[q][m][n]); \
            }                                                                 \
    } while (0)

    bf16x8 af[2][2][2];
    bf16x8 bfr[2][2][2];
    f32x4 acc[4][2][2];
#pragma unroll
    for (int q = 0; q < 4; ++q)
#pragma unroll
        for (int m = 0; m < 2; ++m)
#pragma unroll
            for (int n = 0; n < 2; ++n)
#pragma unroll
                for (int r = 0; r < 4; ++r) acc[q][m][n][r] = 0.f;

    int NT = K >> 6;
    STAGE(Ag0, Abuf[0][0], 0);
    STAGE(Bg0, Bbuf[0][0], 0);
    STAGE(Ag1, Abuf[0][1], 0);
    STAGE(Bg1, Bbuf[0][1], 0);
    STAGE(Ag0, Abuf[1][0], 64);
    STAGE(Bg0, Bbuf[1][0], 64);
    STAGE(Ag1, Abuf[1][1], 64);
    STAGE(Bg1, Bbuf[1][1], 64);
    asm volatile("s_waitcnt vmcnt(8)" ::: "memory");
    __builtin_amdgcn_s_barrier();
#pragma unroll
    for (int m = 0; m < 2; ++m) { RD_A(0, 0, m, 0); RD_A(0, 0, m, 1); }
#pragma unroll
    for (int n = 0; n < 2; ++n) { RD_B(0, 0, n, 0); RD_B(0, 0, n, 1); }

    for (int t = 0; t < NT; ++t) {
        int cur = t & 1, nx = cur ^ 1;
        bool rd = (t + 1 < NT);
        bool st = (t + 2 < NT);
        int ks = (t + 2) << 6;

        // ---- PH0
#pragma unroll
        for (int m = 0; m < 2; ++m) { RD_A(cur, 1, m, 0); RD_A(cur, 1, m, 1); }
        asm volatile("s_waitcnt lgkmcnt(4)" ::: "memory");
        __builtin_amdgcn_sched_barrier(0);
        __builtin_amdgcn_s_setprio(1);
        QUAD(0, 0, 0);
        __builtin_amdgcn_s_setprio(0);

        // ---- PH1
#pragma unroll
        for (int n = 0; n < 2; ++n) { RD_B(cur, 1, n, 0); RD_B(cur, 1, n, 1); }
        asm volatile("s_waitcnt lgkmcnt(4)" ::: "memory");
        __builtin_amdgcn_sched_barrier(0);
        __builtin_amdgcn_s_setprio(1);
        QUAD(1, 1, 0);
        __builtin_amdgcn_s_setprio(0);

        // ---- PH2: single tile-boundary drain
        asm volatile("s_waitcnt lgkmcnt(0)" ::: "memory");
        asm volatile("s_waitcnt vmcnt(0)" ::: "memory");
        __builtin_amdgcn_s_barrier();
        if (st) {
            STAGE(Ag0, Abuf[cur][0], ks);
            STAGE(Bg0, Bbuf[cur][0], ks);
        }
        if (rd) {
#pragma unroll
            for (int n = 0; n < 2; ++n) { RD_B(nx, 0, n, 0); RD_B(nx, 0, n, 1); }
        }
        __builtin_amdgcn_s_setprio(1);
        QUAD(2, 0, 1);
        __builtin_amdgcn_s_setprio(0);

        // ---- PH3
        if (st) {
            STAGE(Ag1, Abuf[cur][1], ks);
            STAGE(Bg1, Bbuf[cur][1], ks);
        }
        if (rd) {
#pragma unroll
            for (int m = 0; m < 2; ++m) { RD_A(nx, 0, m, 0); RD_A(nx, 0, m, 1); }
        }
        __builtin_amdgcn_s_setprio(1);
        QUAD(3, 1, 1);
        __builtin_amdgcn_s_setprio(0);
    }

    // epilogue (f32 out)
#pragma unroll
    for (int q = 0; q < 4; ++q) {
        const int R_ = q & 1, C_ = q >> 1;
#pragma unroll
        for (int m = 0; m < 2; ++m) {
            int row0 = bm * 128 + R_ * 64 + wr * 32 + m * 16 + ((lane >> 4) * 4);
#pragma unroll
            for (int n = 0; n < 2; ++n) {
                int col = bn * 128 + C_ * 64 + wc * 32 + n * 16 + (lane & 15);
#pragma unroll
                for (int rg = 0; rg < 4; ++rg)
                    Cout[(size_t)(row0 + rg) * N + col] = acc[q][m][n][rg];
            }
        }
    }
#undef STAGE
#undef RD_A
#undef RD_B
#undef QUAD
}

// ---------- qkv -> kts (scaled, transposed), vt (transposed); 64x64 tiles ----------
__global__ __launch_bounds__(256) void kv_transpose_kernel(const unsigned short* __restrict__ qkv,
                                                           const float* __restrict__ slopes,
                                                           unsigned short* __restrict__ kts,
                                                           unsigned short* __restrict__ vt) {
    __shared__ unsigned short tk[64][66];
    __shared__ unsigned short tv[64][66];
    int n0 = blockIdx.x * 64, d0 = blockIdx.y * 64, h = blockIdx.z;
    float s = slopes[h];
    int tid = threadIdx.x;
    int tr = tid >> 4;
    int tc4 = (tid & 15) * 4;
#pragma unroll
    for (int it = 0; it < 4; ++it) {
        int r = it * 16 + tr;
        int n = n0 + r;
        size_t rowb = (size_t)n * 12288 + h * 384;
        float sc = __expf(-s * (float)(255 - (n & 255)));
        ushort4 k4 = *(const ushort4*)&qkv[rowb + 128 + d0 + tc4];
        ushort4 v4 = *(const ushort4*)&qkv[rowb + 256 + d0 + tc4];
        tk[r][tc4 + 0] = f2bf(bf2f(k4.x) * sc);
        tk[r][tc4 + 1] = f2bf(bf2f(k4.y) * sc);
        tk[r][tc4 + 2] = f2bf(bf2f(k4.z) * sc);
        tk[r][tc4 + 3] = f2bf(bf2f(k4.w) * sc);
        tv[r][tc4 + 0] = v4.x;
        tv[r][tc4 + 1] = v4.y;
        tv[r][tc4 + 2] = v4.z;
        tv[r][tc4 + 3] = v4.w;
    }
    __syncthreads();
#pragma unroll
    for (int it = 0; it < 4; ++it) {
        int c = it * 16 + tr;
        ushort4 ok, ov;
        ok.x = tk[tc4 + 0][c]; ok.y = tk[tc4 + 1][c];
        ok.z = tk[tc4 + 2][c]; ok.w = tk[tc4 + 3][c];
        ov.x = tv[tc4 + 0][c]; ov.y = tv[tc4 + 1][c];
        ov.z = tv[tc4 + 2][c]; ov.w = tv[tc4 + 3][c];
        size_t ob = (size_t)(h * 128 + d0 + c) * 4096 + n0 + tc4;
        *(ushort4*)&kts[ob] = ok;
        *(ushort4*)&vt[ob] = ov;
    }
}

// ---------- per-block KV outer product (bf16 U out; skip dead U[15]) --------
__global__ __launch_bounds__(256) void kv_outer_kernel(const unsigned short* __restrict__ kts,
                                                       const unsigned short* __restrict__ vt,
                                                       unsigned short* __restrict__ U) {
    __shared__ unsigned short Kc[128 * 64];
    __shared__ unsigned short Vc[128 * 64];
    int blk = blockIdx.x;
    int h = blk & 31, t = blk >> 5;
    int tid = threadIdx.x, lane = tid & 63, w = tid >> 6;

    f32x4 acc[2][8];
#pragma unroll
    for (int m = 0; m < 2; ++m)
#pragma unroll
        for (int n = 0; n < 8; ++n)
#pragma unroll
            for (int r = 0; r < 4; ++r) acc[m][n][r] = 0.f;

    for (int ks = 0; ks < 4; ++ks) {
        __syncthreads();
#pragma unroll
        for (int it = 0; it < 4; ++it) {
            int slot = it * 256 + tid;
            int o = slot * 16;
            int r = o >> 7;
            int cb = o & 127;
            int scb = cb ^ ((r & 7) << 4);
            size_t j = (size_t)t * 256 + ks * 64 + (scb >> 1);
            gl16(kts + (size_t)(h * 128 + r) * 4096 + j, (char*)Kc + o);
            gl16(vt + (size_t)(h * 128 + r) * 4096 + j, (char*)Vc + o);
        }
        __syncthreads();
#pragma unroll
        for (int kk = 0; kk < 2; ++kk) {
            int kb = kk * 64 + ((lane >> 4) * 16);
            bf16x8 vf[2], kf[8];
#pragma unroll
            for (int m = 0; m < 2; ++m) {
                int e = w * 32 + m * 16 + (lane & 15);
                vf[m] = *(const bf16x8*)((const char*)Vc + (e << 7) + (kb ^ ((e & 7) << 4)));
            }
#pragma unroll
            for (int n = 0; n < 8; ++n) {
                int d = n * 16 + (lane & 15);
                kf[n] = *(const bf16x8*)((const char*)Kc + (d << 7) + (kb ^ ((d & 7) << 4)));
            }
#pragma unroll
            for (int m = 0; m < 2; ++m)
#pragma unroll
                for (int n = 0; n < 8; ++n)
                    acc[m][n] = MFMA16(vf[m], kf[n], acc[m][n]);
        }
    }
    if (t == 15) return;   // U[h][15] only feeds the dead post-loop state
    size_t base = (size_t)(h * 16 + t) * 16384;
#pragma unroll
    for (int m = 0; m < 2; ++m)
#pragma unroll
        for (int n = 0; n < 8; ++n)
#pragma unroll
            for (int r = 0; r < 4; ++r) {
                int e = w * 32 + m * 16 + ((lane >> 4) * 4) + r;
                int d = n * 16 + (lane & 15);
                U[base + (size_t)e * 128 + d] = f2bf(acc[m][n][r]);
            }
}

// ---------- parallel scan: 32 heads x 16 chunks of 1024 (bf16 U in) ---------
__global__ __launch_bounds__(256) void kv_scan_kernel(const float* __restrict__ kv_cache,
                                                      const unsigned short* __restrict__ U,
                                                      const float* __restrict__ slopes,
                                                      unsigned short* __restrict__ Wb) {
    __shared__ float Tt[8][132];
    int h = blockIdx.x >> 4;
    int c = blockIdx.x & 15;
    int c0 = c * 1024, e0 = c * 8;
    int tid = threadIdx.x;
    float s = slopes[h];
    float bd = __expf(-s * 256.f);
    size_t hb = (size_t)h * 16384;
#pragma unroll
    for (int it = 0; it < 4; ++it) {
        int d = it * 32 + (tid >> 3);
        Tt[tid & 7][d] = kv_cache[hb + (size_t)d * 128 + e0 + (tid & 7)];
    }
    __syncthreads();
    float wst[4];
#pragma unroll
    for (int i = 0; i < 4; ++i) {
        int local = i * 256 + tid;
        wst[i] = Tt[local >> 7][local & 127];
    }
    for (int t = 0; t < 16; ++t) {
        size_t base = (size_t)(h * 16 + t) * 16384 + c0;
#pragma unroll
        for (int i = 0; i < 4; ++i) {
            int idx = i * 256 + tid;
            Wb[base + idx] = f2bf(wst[i]);
            if (t < 15) wst[i] = bd * wst[i] + bf2f(U[base + idx]);
        }
    }
}

// ---------- fused attention block kernel: QBLK=128, 80KB LDS, 2 WG/CU ----------
__global__ __launch_bounds__(256, 2) void attn_out_kernel(const unsigned short* __restrict__ qkv,
                                                          const unsigned short* __restrict__ vt,
                                                          const unsigned short* __restrict__ Wb,
                                                          const float* __restrict__ slopes,
                                                          unsigned short* __restrict__ attn) {
    __shared__ unsigned short lds[40960];  // 80 KB
    unsigned short* Qs = lds;
    unsigned short* Ps = lds + 16384;
    unsigned short* KW = lds + 24576;
    unsigned short* Ks = KW;
    unsigned short* Vs = KW + 8192;

    int blk = blockIdx.x;
    int h = blk & 31, tq = blk >> 5;
    int t = tq >> 1, qh = tq & 1;
    float s = slopes[h];
    int tid = threadIdx.x, lane = tid & 63, w = tid >> 6;
    int rowbase = t * 256 + qh * 128;

#pragma unroll
    for (int it = 0; it < 8; ++it) {
        int o = (it * 256 + tid) * 16;
        int r = o >> 8, cb = o & 255, scb = cb ^ ((r & 7) << 4);
        gl16(qkv + (size_t)(rowbase + r) * 12288 + h * 384 + (scb >> 1), (char*)Qs + o);
    }
#pragma unroll
    for (int it = 0; it < 8; ++it) {
        int o = (it * 256 + tid) * 16;
        int e = o >> 8, cb = o & 255, scb = cb ^ ((e & 7) << 4);
        gl16(Wb + (size_t)((h * 16 + t) * 128 + e) * 128 + (scb >> 1), (char*)KW + o);
    }
    __syncthreads();

    f32x4 acc[2][8];
#pragma unroll
    for (int m = 0; m < 2; ++m)
#pragma unroll
        for (int n = 0; n < 8; ++n)
#pragma unroll
            for (int r = 0; r < 4; ++r) acc[m][n][r] = 0.f;

#pragma unroll
    for (int kk = 0; kk < 4; ++kk) {
        int kb = kk * 64 + ((lane >> 4) * 16);
        bf16x8 qf[2], wf[8];
#pragma unroll
        for (int m = 0; m < 2; ++m) {
            int r = w * 32 + m * 16 + (lane & 15);
            qf[m] = *(const bf16x8*)((const char*)Qs + (r << 8) + (kb ^ ((r & 7) << 4)));
        }
#pragma unroll
        for (int n = 0; n < 8; ++n) {
            int e = n * 16 + (lane & 15);
            wf[n] = *(const bf16x8*)((const char*)KW + (e << 8) + (kb ^ ((e & 7) << 4)));
        }
#pragma unroll
        for (int m = 0; m < 2; ++m)
#pragma unroll
            for (int n = 0; n < 8; ++n)
                acc[m][n] = MFMA16(qf[m], wf[n], acc[m][n]);
    }
#pragma unroll
    for (int m = 0; m < 2; ++m)
#pragma unroll
        for (int rg = 0; rg < 4; ++rg) {
            int i = qh * 128 + w * 32 + m * 16 + ((lane >> 4) * 4) + rg;
            float qd = __expf(-s * (float)(i + 1));
#pragma unroll
            for (int n = 0; n < 8; ++n) acc[m][n][rg] *= qd;
        }

    int jbmax = ((qh << 2) + w) >> 1;
    for (int jb = 0; jb < 4; ++jb) {
        __syncthreads();
#pragma unroll
        for (int it = 0; it < 4; ++it) {
            int o = (it * 256 + tid) * 16;
            int r = o >> 8, cb = o & 255, scb = cb ^ ((r & 7) << 4);
            gl16(qkv + (size_t)(t * 256 + jb * 64 + r) * 12288 + h * 384 + 128 + (scb >> 1),
                 (char*)Ks + o);
        }
#pragma unroll
        for (int it = 0; it < 4; ++it) {
            int o = (it * 256 + tid) * 16;
            int e = o >> 7, cb = o & 127, scb = cb ^ ((e & 7) << 4);
            gl16(vt + (size_t)(h * 128 + e) * 4096 + t * 256 + jb * 64 + (scb >> 1),
                 (char*)Vs + o);
        }
        __syncthreads();

        if (jb <= jbmax) {
            f32x4 sc[2][4];
#pragma unroll
            for (int m = 0; m < 2; ++m)
#pragma unroll
                for (int n = 0; n < 4; ++n)
#pragma unroll
                    for (int r = 0; r < 4; ++r) sc[m][n][r] = 0.f;
#pragma unroll
            for (int kk = 0; kk < 4; ++kk) {
                int kb = kk * 64 + ((lane >> 4) * 16);
                bf16x8 qf[2], kf[4];
#pragma unroll
                for (int m = 0; m < 2; ++m) {
                    int r = w * 32 + m * 16 + (lane & 15);
                    qf[m] = *(const bf16x8*)((const char*)Qs + (r << 8) + (kb ^ ((r & 7) << 4)));
                }
#pragma unroll
                for (int n = 0; n < 4; ++n) {
                    int r = n * 16 + (lane & 15);
                    kf[n] = *(const bf16x8*)((const char*)Ks + (r << 8) + (kb ^ ((r & 7) << 4)));
                }
#pragma unroll
                for (int m = 0; m < 2; ++m)
#pragma unroll
                    for (int n = 0; n < 4; ++n)
                        sc[m][n] = MFMA16(qf[m], kf[n], sc[m][n]);
            }
            unsigned short* Pw = Ps + w * 2048;
#pragma unroll
            for (int m = 0; m < 2; ++m)
#pragma unroll
                for (int n = 0; n < 4; ++n)
#pragma unroll
                    for (int rg = 0; rg < 4; ++rg) {
                        int il = m * 16 + ((lane >> 4) * 4) + rg;
                        int i = qh * 128 + w * 32 + il;
                        int jl = n * 16 + (lane & 15);
                        int j = jb * 64 + jl;
                        float v = 0.f;
                        if (i >= j) v = sc[m][n][rg] * __expf(-s * (float)(i - j));
                        int cb2 = (jl * 2) ^ ((il & 7) << 4);
                        *(unsigned short*)((char*)Pw + (il << 7) + cb2) = f2bf(v);
                    }
            asm volatile("s_waitcnt lgkmcnt(0)" ::: "memory");
#pragma unroll
            for (int kk = 0; kk < 2; ++kk) {
                int kb = kk * 64 + ((lane >> 4) * 16);
                bf16x8 pf[2], vf[8];
#pragma unroll
                for (int m = 0; m < 2; ++m) {
                    int il = m * 16 + (lane & 15);
                    pf[m] = *(const bf16x8*)((const char*)Pw + (il << 7) + (kb ^ ((il & 7) << 4)));
                }
#pragma unroll
                for (int n = 0; n < 8; ++n) {
                    int e = n * 16 + (lane & 15);
                    vf[n] = *(const bf16x8*)((const char*)Vs + (e << 7) + (kb ^ ((e & 7) << 4)));
                }
#pragma unroll
                for (int m = 0; m < 2; ++m)
#pragma unroll
                    for (int n = 0; n < 8; ++n)
                        acc[m][n] = MFMA16(pf[m], vf[n], acc[m][n]);
            }
        }
    }

#pragma unroll
    for (int m = 0; m < 2; ++m)
#pragma unroll
        for (int n = 0; n < 8; ++n)
#pragma unroll
            for (int rg = 0; rg < 4; ++rg) {
                int i = qh * 128 + w * 32 + m * 16 + ((lane >> 4) * 4) + rg;
                int col = h * 128 + n * 16 + (lane & 15);
                attn[(size_t)(t * 256 + i) * 4096 + col] = f2bf(acc[m][n][rg]);
            }
}

// ---------- RMSNorm + sigmoid-gate multiply ----------
__global__ __launch_bounds__(256) void rms_gate_kernel(const unsigned short* __restrict__ attn,
                                                       const unsigned short* __restrict__ gate,
                                                       const float* __restrict__ nw,
                                                       unsigned short* __restrict__ gated) {
    int row = blockIdx.x, tid = threadIdx.x;
    int lane = tid & 63, w = tid >> 6;
    const unsigned short* ar = attn + (size_t)row * 4096 + tid * 16;
    u16x8 a0 = *(const u16x8*)ar;
    u16x8 a1 = *(const u16x8*)(ar + 8);
    float v[16];
    float ss = 0.f;
#pragma unroll
    for (int j = 0; j < 8; ++j) { v[j] = bf2f(a0[j]); v[8 + j] = bf2f(a1[j]); }
#pragma unroll
    for (int j = 0; j < 16; ++j) ss += v[j] * v[j];
#pragma unroll
    for (int o = 32; o > 0; o >>= 1) ss += __shfl_xor(ss, o);
    __shared__ float red[4];
    if (lane == 0) red[w] = ss;
    __syncthreads();
    float tot = red[0] + red[1] + red[2] + red[3];
    float rs = rsqrtf(tot * (1.f / 4096.f) + 1e-5f);
    const unsigned short* gr = gate + (size_t)row * 4096 + tid * 16;
    u16x8 g0 = *(const u16x8*)gr;
    u16x8 g1 = *(const u16x8*)(gr + 8);
    const float* nwp = nw + tid * 16;
    u16x8 o0, o1;
#pragma unroll
    for (int j = 0; j < 8; ++j) {
        o0[j] = f2bf(v[j] * rs * nwp[j] * bf2f(g0[j]));
        o1[j] = f2bf(v[8 + j] * rs * nwp[8 + j] * bf2f(g1[j]));
    }
    unsigned short* gp = gated + (size_t)row * 4096 + tid * 16;
    *(u16x8*)gp = o0;
    *(u16x8*)(gp + 8) = o1;
}

// ---------- launcher ----------
extern "C" void kernel_launch(void* const* d_in, const int* in_sizes, int n_in,
                              void* d_out, int out_size, void* d_ws, size_t ws_size,
                              hipStream_t stream) {
    const float* hs       = (const float*)d_in[0];
    const float* w_qkv    = (const float*)d_in[1];
    const float* w_gate   = (const float*)d_in[2];
    const float* w_out    = (const float*)d_in[3];
    const float* nw       = (const float*)d_in[4];
    const float* slopes   = (const float*)d_in[5];
    const float* kv_cache = (const float*)d_in[6];
    float* out = (float*)d_out;
    char* ws = (char*)d_ws;

    unsigned short* hsb  = (unsigned short*)(ws + 0);
    unsigned short* wqt  = (unsigned short*)(ws + 16777216);
    unsigned short* wgt  = (unsigned short*)(ws + 67108864);
    unsigned short* wot  = (unsigned short*)(ws + 83886080);
    unsigned short* qkv  = (unsigned short*)(ws + 100663296);
    unsigned short* gate = (unsigned short*)(ws + 201326592);
    unsigned short* kts  = (unsigned short*)(ws + 234881024);
    unsigned short* vt   = (unsigned short*)(ws + 268435456);
    unsigned short* U    = (unsigned short*)(ws + 301989888);  // 16 MB bf16
    unsigned short* Wb   = (unsigned short*)(ws + 335544320);
    unsigned short* attn  = wqt;  // reuse
    unsigned short* gated = qkv;  // reuse

    prep_kernel<<<14336, 256, 0, stream>>>(hs, w_qkv, w_gate, w_out, hsb, wqt, wgt, wot);
    gemm_qkvgate_kernel<<<1024, 512, 0, stream>>>(hsb, wqt, qkv, gate, 2048, 64, 48);
    {
        dim3 g(64, 2, 32);
        kv_transpose_kernel<<<g, 256, 0, stream>>>(qkv, slopes, kts, vt);
    }
    kv_outer_kernel<<<512, 256, 0, stream>>>(kts, vt, U);
    kv_scan_kernel<<<512, 256, 0, stream>>>(kv_cache, U, slopes, Wb);
    attn_out_kernel<<<1024, 256, 0, stream>>>(qkv, vt, Wb, slopes, attn);
    rms_gate_kernel<<<4096, 256, 0, stream>>>(attn, gate, nw, gated);
    gemm_out_kernel<<<512, 256, 0, stream>>>(gated, wot, out, 2048, 4096, 16);
}

// Round 17
// 462.088 us; speedup vs baseline: 1.0996x; 1.0011x over previous
//
#include <hip/hip_runtime.h>
#include <stdint.h>

// ---------- types & helpers ----------
typedef __bf16 bf16x8 __attribute__((ext_vector_type(8)));
typedef float  f32x4  __attribute__((ext_vector_type(4)));
typedef unsigned short u16x8 __attribute__((ext_vector_type(8)));

__device__ __forceinline__ unsigned short f2bf(float f) {
    union { float f; uint32_t u; } x; x.f = f;
    uint32_t r = (x.u + 0x7FFFu + ((x.u >> 16) & 1u)) >> 16;
    return (unsigned short)r;
}
__device__ __forceinline__ float bf2f(unsigned short b) {
    union { uint32_t u; float f; } x; x.u = ((uint32_t)b) << 16;
    return x.f;
}

// global -> LDS direct (16B per lane). LDS dest: wave-uniform base + lane*16.
__device__ __forceinline__ void gl16(const void* g, void* l) {
    __builtin_amdgcn_global_load_lds(
        (const __attribute__((address_space(1))) void*)g,
        (__attribute__((address_space(3))) void*)(uint32_t)(uintptr_t)l,
        16, 0, 0);
}

#define MFMA16(a, b, c) __builtin_amdgcn_mfma_f32_16x16x32_bf16((a), (b), (c), 0, 0, 0)

// ---------- merged prep: hs f32->bf16 + 3 weight transposes ----------
__global__ __launch_bounds__(256) void prep_kernel(const float* __restrict__ hs,
                                                   const float* __restrict__ w_qkv,
                                                   const float* __restrict__ w_gate,
                                                   const float* __restrict__ w_out,
                                                   unsigned short* __restrict__ hsb,
                                                   unsigned short* __restrict__ wqt,
                                                   unsigned short* __restrict__ wgt,
                                                   unsigned short* __restrict__ wot) {
    __shared__ float tile[64][65];
    int b = blockIdx.x, tid = threadIdx.x;
    if (b >= 10240) {
        int i = (b - 10240) * 256 + tid;
        float4 a = ((const float4*)hs)[2 * i];
        float4 c = ((const float4*)hs)[2 * i + 1];
        u16x8 o;
        o[0] = f2bf(a.x); o[1] = f2bf(a.y); o[2] = f2bf(a.z); o[3] = f2bf(a.w);
        o[4] = f2bf(c.x); o[5] = f2bf(c.y); o[6] = f2bf(c.z); o[7] = f2bf(c.w);
        ((u16x8*)hsb)[i] = o;
        return;
    }
    const float* in; unsigned short* out; int R, C, bx, by;
    if (b < 6144)      { in = w_qkv;  out = wqt; R = 2048; C = 12288; bx = b % 192; by = b / 192; }
    else if (b < 8192) { int bb = b - 6144; in = w_gate; out = wgt; R = 2048; C = 4096; bx = bb % 64; by = bb / 64; }
    else               { int bb = b - 8192; in = w_out;  out = wot; R = 4096; C = 2048; bx = bb % 32; by = bb / 32; }
    int c0 = bx * 64, r0 = by * 64;
    int tr = tid >> 4;
    int tc4 = (tid & 15) * 4;
#pragma unroll
    for (int it = 0; it < 4; ++it) {
        int r = it * 16 + tr;
        float4 v = *(const float4*)&in[(size_t)(r0 + r) * C + c0 + tc4];
        tile[r][tc4] = v.x; tile[r][tc4 + 1] = v.y;
        tile[r][tc4 + 2] = v.z; tile[r][tc4 + 3] = v.w;
    }
    __syncthreads();
#pragma unroll
    for (int it = 0; it < 4; ++it) {
        int c = it * 16 + tr;
        ushort4 o;
        o.x = f2bf(tile[tc4][c]);
        o.y = f2bf(tile[tc4 + 1][c]);
        o.z = f2bf(tile[tc4 + 2][c]);
        o.w = f2bf(tile[tc4 + 3][c]);
        *(ushort4*)&out[(size_t)(c0 + c) * R + r0 + tc4] = o;
    }
}

// ====== 256x256 register-pipelined 4-phase GEMM, fused qkv+gate (R10) =======
__global__ __launch_bounds__(512, 2) void gemm_qkvgate_kernel(const unsigned short* __restrict__ A,
                                                              const unsigned short* __restrict__ Bt,
                                                              unsigned short* __restrict__ qkvp,
                                                              unsigned short* __restrict__ gatep,
                                                              int K, int NBN, int NQ) {
    __shared__ unsigned short Abuf[2][2][8192];
    __shared__ unsigned short Bbuf[2][2][8192];

    int bid = blockIdx.x;
    int xcd = bid & 7, kw = bid >> 3;
    int bm = (xcd & 3) * 4 + (kw & 3);
    int bn = (xcd >> 2) * (NBN >> 1) + (kw >> 2);
    int tid = threadIdx.x, lane = tid & 63, w = tid >> 6;
    int wr = w >> 2, wc = w & 3;

    int r0 = tid >> 3;
    int cbs = (tid & 7) << 4;
    int el0 = (cbs ^ ((r0 & 7) << 4)) >> 1;
    int r1 = 64 + r0;
    int el1 = (cbs ^ ((r1 & 7) << 4)) >> 1;
    int lo0 = tid * 16, lo1 = 8192 + tid * 16;

    const unsigned short* Ag0 = A + (size_t)(bm * 256) * K;
    const unsigned short* Ag1 = A + (size_t)(bm * 256 + 128) * K;
    const unsigned short* Bg0 = Bt + (size_t)(bn * 256) * K;
    const unsigned short* Bg1 = Bt + (size_t)(bn * 256 + 128) * K;

#define STAGE(src, dstHalf, k0)                                            \
    do {                                                                   \
        gl16((src) + (size_t)r0 * K + (k0) + el0, (char*)(dstHalf) + lo0); \
        gl16((src) + (size_t)r1 * K + (k0) + el1, (char*)(dstHalf) + lo1); \
    } while (0)

    int aRow = wr * 64 + (lane & 15);
    int bRow = wc * 32 + (lane & 15);
    int swz = (lane & 7) << 4;
    int cbb = (lane >> 4) << 4;

#define RD_A(slot, R, m, kk) \
    af[R][m][kk] = *(const bf16x8*)((const char*)Abuf[slot][R] + ((aRow + (m) * 16) << 7) + (((kk) * 64 + cbb) ^ swz))
#define RD_B(slot, Cq, n, kk) \
    bfr[Cq][n][kk] = *(const bf16x8*)((const char*)Bbuf[slot][Cq] + ((bRow + (n) * 16) << 7) + (((kk) * 64 + cbb) ^ swz))

#define QUAD(q, Rh, Cc)                                                       \
    do {                                                                      \
        _Pragma("unroll")                                                     \
        for (int m = 0; m < 4; ++m)                                           \
            _Pragma("unroll")                                                 \
            for (int n = 0; n < 2; ++n) {                                     \
                acc[q][m][n] = MFMA16(af[Rh][m][0], bfr[Cc][n][0], acc[q][m][n]); \
                acc[q][m][n] = MFMA16(af[Rh][m][1], bfr[Cc][n][1], acc[q][m][n]); \
            }                                                                 \
    } while (0)

    bf16x8 af[2][4][2];
    bf16x8 bfr[2][2][2];
    f32x4 acc[4][4][2];
#pragma unroll
    for (int q = 0; q < 4; ++q)
#pragma unroll
        for (int m = 0; m < 4; ++m)
#pragma unroll
            for (int n = 0; n < 2; ++n)
#pragma unroll
                for (int r = 0; r < 4; ++r) acc[q][m][n][r] = 0.f;

    int NT = K >> 6;
    STAGE(Ag0, Abuf[0][0], 0);
    STAGE(Bg0, Bbuf[0][0], 0);
    STAGE(Ag1, Abuf[0][1], 0);
    STAGE(Bg1, Bbuf[0][1], 0);
    STAGE(Ag0, Abuf[1][0], 64);
    STAGE(Bg0, Bbuf[1][0], 64);
    STAGE(Ag1, Abuf[1][1], 64);
    STAGE(Bg1, Bbuf[1][1], 64);
    asm volatile("s_waitcnt vmcnt(8)" ::: "memory");
    __builtin_amdgcn_s_barrier();
#pragma unroll
    for (int m = 0; m < 4; ++m) { RD_A(0, 0, m, 0); RD_A(0, 0, m, 1); }
#pragma unroll
    for (int n = 0; n < 2; ++n) { RD_B(0, 0, n, 0); RD_B(0, 0, n, 1); }

    for (int t = 0; t < NT; ++t) {
        int cur = t & 1, nx = cur ^ 1;
        bool rd = (t + 1 < NT);
        bool st = (t + 2 < NT);
        int ks = (t + 2) << 6;

        // ---- PH0
#pragma unroll
        for (int m = 0; m < 4; ++m) { RD_A(cur, 1, m, 0); RD_A(cur, 1, m, 1); }
        asm volatile("s_waitcnt lgkmcnt(8)" ::: "memory");
        __builtin_amdgcn_sched_barrier(0);
        __builtin_amdgcn_s_setprio(1);
        QUAD(0, 0, 0);
        __builtin_amdgcn_s_setprio(0);

        // ---- PH1
#pragma unroll
        for (int n = 0; n < 2; ++n) { RD_B(cur, 1, n, 0); RD_B(cur, 1, n, 1); }
        asm volatile("s_waitcnt lgkmcnt(4)" ::: "memory");
        __builtin_amdgcn_sched_barrier(0);
        __builtin_amdgcn_s_setprio(1);
        QUAD(1, 1, 0);
        __builtin_amdgcn_s_setprio(0);

        // ---- PH2: single tile-boundary drain
        asm volatile("s_waitcnt lgkmcnt(0)" ::: "memory");
        asm volatile("s_waitcnt vmcnt(0)" ::: "memory");
        __builtin_amdgcn_s_barrier();
        if (st) {
            STAGE(Ag0, Abuf[cur][0], ks);
            STAGE(Bg0, Bbuf[cur][0], ks);
        }
        if (rd) {
#pragma unroll
            for (int n = 0; n < 2; ++n) { RD_B(nx, 0, n, 0); RD_B(nx, 0, n, 1); }
        }
        __builtin_amdgcn_s_setprio(1);
        QUAD(2, 0, 1);
        __builtin_amdgcn_s_setprio(0);

        // ---- PH3
        if (st) {
            STAGE(Ag1, Abuf[cur][1], ks);
            STAGE(Bg1, Bbuf[cur][1], ks);
        }
        if (rd) {
#pragma unroll
            for (int m = 0; m < 4; ++m) { RD_A(nx, 0, m, 0); RD_A(nx, 0, m, 1); }
        }
        __builtin_amdgcn_s_setprio(1);
        QUAD(3, 1, 1);
        __builtin_amdgcn_s_setprio(0);
    }

    // epilogue: block-uniform output select
    bool isQ = (bn < NQ);
    unsigned short* outp = isQ ? qkvp : gatep;
    int Nout = isQ ? 12288 : 4096;
    int colb0 = (isQ ? bn : bn - NQ) * 256;
#pragma unroll
    for (int q = 0; q < 4; ++q) {
        const int R_ = q & 1, C_ = q >> 1;
#pragma unroll
        for (int m = 0; m < 4; ++m) {
            int row0 = bm * 256 + R_ * 128 + wr * 64 + m * 16 + ((lane >> 4) * 4);
#pragma unroll
            for (int n = 0; n < 2; ++n) {
                int col = colb0 + C_ * 128 + wc * 32 + n * 16 + (lane & 15);
#pragma unroll
                for (int rg = 0; rg < 4; ++rg) {
                    float v = acc[q][m][n][rg];
                    float sig = 1.f / (1.f + __expf(-v));
                    float r = isQ ? v * sig : sig;
                    outp[(size_t)(row0 + rg) * Nout + col] = f2bf(r);
                }
            }
        }
    }
#undef STAGE
#undef RD_A
#undef RD_B
#undef QUAD
}

// ====== 128x128 pipelined out-GEMM (R10) ====================================
__global__ __launch_bounds__(256, 2) void gemm_out_kernel(const unsigned short* __restrict__ A,
                                                          const unsigned short* __restrict__ Bt,
                                                          float* __restrict__ Cout,
                                                          int N, int K, int NBN) {
    __shared__ unsigned short Abuf[2][2][4096];
    __shared__ unsigned short Bbuf[2][2][4096];

    int bid = blockIdx.x, nwg = gridDim.x;
    int wg = (bid & 7) * (nwg >> 3) + (bid >> 3);
    int bm = wg / NBN, bn = wg % NBN;
    int tid = threadIdx.x, lane = tid & 63, w = tid >> 6;
    int wr = w >> 1, wc = w & 1;

    int r0 = tid >> 3;
    int cbs = (tid & 7) << 4;
    int el0 = (cbs ^ ((r0 & 7) << 4)) >> 1;
    int r1 = 32 + r0;
    int el1 = (cbs ^ ((r1 & 7) << 4)) >> 1;
    int lo0 = tid * 16, lo1 = 4096 + tid * 16;

    const unsigned short* Ag0 = A + (size_t)(bm * 128) * K;
    const unsigned short* Ag1 = A + (size_t)(bm * 128 + 64) * K;
    const unsigned short* Bg0 = Bt + (size_t)(bn * 128) * K;
    const unsigned short* Bg1 = Bt + (size_t)(bn * 128 + 64) * K;

#define STAGE(src, dstHalf, k0)                                            \
    do {                                                                   \
        gl16((src) + (size_t)r0 * K + (k0) + el0, (char*)(dstHalf) + lo0); \
        gl16((src) + (size_t)r1 * K + (k0) + el1, (char*)(dstHalf) + lo1); \
    } while (0)

    int aRow = wr * 32 + (lane & 15);
    int bRow = wc * 32 + (lane & 15);
    int swz = (lane & 7) << 4;
    int cbb = (lane >> 4) << 4;

#define RD_A(slot, R, m, kk) \
    af[R][m][kk] = *(const bf16x8*)((const char*)Abuf[slot][R] + ((aRow + (m) * 16) << 7) + (((kk) * 64 + cbb) ^ swz))
#define RD_B(slot, Cq, n, kk) \
    bfr[Cq][n][kk] = *(const bf16x8*)((const char*)Bbuf[slot][Cq] + ((bRow + (n) * 16) << 7) + (((kk) * 64 + cbb) ^ swz))

#define QUAD(q, Rh, Cc)                                                       \
    do {                                                                      \
        _Pragma("unroll")                                                     \
        for (int m = 0; m < 2; ++m)                                           \
            _Pragma("unroll")                                                 \
            for (int n = 0; n < 2; ++n) {                                     \
                acc[q][m][n] = MFMA16(af[Rh][m][0], bfr[Cc][n][0], acc[q][m][n]); \
                acc[q][m][n] = MFMA16(af[Rh][m][1], bfr[Cc][n][1], acc[q][m][n]); \
            }                                                                 \
    } while (0)

    bf16x8 af[2][2][2];
    bf16x8 bfr[2][2][2];
    f32x4 acc[4][2][2];
#pragma unroll
    for (int q = 0; q < 4; ++q)
#pragma unroll
        for (int m = 0; m < 2; ++m)
#pragma unroll
            for (int n = 0; n < 2; ++n)
#pragma unroll
                for (int r = 0; r < 4; ++r) acc[q][m][n][r] = 0.f;

    int NT = K >> 6;
    STAGE(Ag0, Abuf[0][0], 0);
    STAGE(Bg0, Bbuf[0][0], 0);
    STAGE(Ag1, Abuf[0][1], 0);
    STAGE(Bg1, Bbuf[0][1], 0);
    STAGE(Ag0, Abuf[1][0], 64);
    STAGE(Bg0, Bbuf[1][0], 64);
    STAGE(Ag1, Abuf[1][1], 64);
    STAGE(Bg1, Bbuf[1][1], 64);
    asm volatile("s_waitcnt vmcnt(8)" ::: "memory");
    __builtin_amdgcn_s_barrier();
#pragma unroll
    for (int m = 0; m < 2; ++m) { RD_A(0, 0, m, 0); RD_A(0, 0, m, 1); }
#pragma unroll
    for (int n = 0; n < 2; ++n) { RD_B(0, 0, n, 0); RD_B(0, 0, n, 1); }

    for (int t = 0; t < NT; ++t) {
        int cur = t & 1, nx = cur ^ 1;
        bool rd = (t + 1 < NT);
        bool st = (t + 2 < NT);
        int ks = (t + 2) << 6;

        // ---- PH0
#pragma unroll
        for (int m = 0; m < 2; ++m) { RD_A(cur, 1, m, 0); RD_A(cur, 1, m, 1); }
        asm volatile("s_waitcnt lgkmcnt(4)" ::: "memory");
        __builtin_amdgcn_sched_barrier(0);
        __builtin_amdgcn_s_setprio(1);
        QUAD(0, 0, 0);
        __builtin_amdgcn_s_setprio(0);

        // ---- PH1
#pragma unroll
        for (int n = 0; n < 2; ++n) { RD_B(cur, 1, n, 0); RD_B(cur, 1, n, 1); }
        asm volatile("s_waitcnt lgkmcnt(4)" ::: "memory");
        __builtin_amdgcn_sched_barrier(0);
        __builtin_amdgcn_s_setprio(1);
        QUAD(1, 1, 0);
        __builtin_amdgcn_s_setprio(0);

        // ---- PH2: single tile-boundary drain
        asm volatile("s_waitcnt lgkmcnt(0)" ::: "memory");
        asm volatile("s_waitcnt vmcnt(0)" ::: "memory");
        __builtin_amdgcn_s_barrier();
        if (st) {
            STAGE(Ag0, Abuf[cur][0], ks);
            STAGE(Bg0, Bbuf[cur][0], ks);
        }
        if (rd) {
#pragma unroll
            for (int n = 0; n < 2; ++n) { RD_B(nx, 0, n, 0); RD_B(nx, 0, n, 1); }
        }
        __builtin_amdgcn_s_setprio(1);
        QUAD(2, 0, 1);
        __builtin_amdgcn_s_setprio(0);

        // ---- PH3
        if (st) {
            STAGE(Ag1, Abuf[cur][1], ks);
            STAGE(Bg1, Bbuf[cur][1], ks);
        }
        if (rd) {
#pragma unroll
            for (int m = 0; m < 2; ++m) { RD_A(nx, 0, m, 0); RD_A(nx, 0, m, 1); }
        }
        __builtin_amdgcn_s_setprio(1);
        QUAD(3, 1, 1);
        __builtin_amdgcn_s_setprio(0);
    }

    // epilogue (f32 out)
#pragma unroll
    for (int q = 0; q < 4; ++q) {
        const int R_ = q & 1, C_ = q >> 1;
#pragma unroll
        for (int m = 0; m < 2; ++m) {
            int row0 = bm * 128 + R_ * 64 + wr * 32 + m * 16 + ((lane >> 4) * 4);
#pragma unroll
            for (int n = 0; n < 2; ++n) {
                int col = bn * 128 + C_ * 64 + wc * 32 + n * 16 + (lane & 15);
#pragma unroll
                for (int rg = 0; rg < 4; ++rg)
                    Cout[(size_t)(row0 + rg) * N + col] = acc[q][m][n][rg];
            }
        }
    }
#undef STAGE
#undef RD_A
#undef RD_B
#undef QUAD
}

// ---------- qkv -> kts (scaled, transposed), vt (transposed); 64x64 tiles ----------
__global__ __launch_bounds__(256) void kv_transpose_kernel(const unsigned short* __restrict__ qkv,
                                                           const float* __restrict__ slopes,
                                                           unsigned short* __restrict__ kts,
                                                           unsigned short* __restrict__ vt) {
    __shared__ unsigned short tk[64][66];
    __shared__ unsigned short tv[64][66];
    int n0 = blockIdx.x * 64, d0 = blockIdx.y * 64, h = blockIdx.z;
    float s = slopes[h];
    int tid = threadIdx.x;
    int tr = tid >> 4;
    int tc4 = (tid & 15) * 4;
#pragma unroll
    for (int it = 0; it < 4; ++it) {
        int r = it * 16 + tr;
        int n = n0 + r;
        size_t rowb = (size_t)n * 12288 + h * 384;
        float sc = __expf(-s * (float)(255 - (n & 255)));
        ushort4 k4 = *(const ushort4*)&qkv[rowb + 128 + d0 + tc4];
        ushort4 v4 = *(const ushort4*)&qkv[rowb + 256 + d0 + tc4];
        tk[r][tc4 + 0] = f2bf(bf2f(k4.x) * sc);
        tk[r][tc4 + 1] = f2bf(bf2f(k4.y) * sc);
        tk[r][tc4 + 2] = f2bf(bf2f(k4.z) * sc);
        tk[r][tc4 + 3] = f2bf(bf2f(k4.w) * sc);
        tv[r][tc4 + 0] = v4.x;
        tv[r][tc4 + 1] = v4.y;
        tv[r][tc4 + 2] = v4.z;
        tv[r][tc4 + 3] = v4.w;
    }
    __syncthreads();
#pragma unroll
    for (int it = 0; it < 4; ++it) {
        int c = it * 16 + tr;
        ushort4 ok, ov;
        ok.x = tk[tc4 + 0][c]; ok.y = tk[tc4 + 1][c];
        ok.z = tk[tc4 + 2][c]; ok.w = tk[tc4 + 3][c];
        ov.x = tv[tc4 + 0][c]; ov.y = tv[tc4 + 1][c];
        ov.z = tv[tc4 + 2][c]; ov.w = tv[tc4 + 3][c];
        size_t ob = (size_t)(h * 128 + d0 + c) * 4096 + n0 + tc4;
        *(ushort4*)&kts[ob] = ok;
        *(ushort4*)&vt[ob] = ov;
    }
}

// ---------- per-block KV outer product (bf16 U out; grid 480 = 32h x 15t) ---
__global__ __launch_bounds__(256) void kv_outer_kernel(const unsigned short* __restrict__ kts,
                                                       const unsigned short* __restrict__ vt,
                                                       unsigned short* __restrict__ U) {
    __shared__ unsigned short Kc[128 * 64];
    __shared__ unsigned short Vc[128 * 64];
    int blk = blockIdx.x;
    int h = blk & 31, t = blk >> 5;   // t in [0,15)
    int tid = threadIdx.x, lane = tid & 63, w = tid >> 6;

    f32x4 acc[2][8];
#pragma unroll
    for (int m = 0; m < 2; ++m)
#pragma unroll
        for (int n = 0; n < 8; ++n)
#pragma unroll
            for (int r = 0; r < 4; ++r) acc[m][n][r] = 0.f;

    for (int ks = 0; ks < 4; ++ks) {
        __syncthreads();
#pragma unroll
        for (int it = 0; it < 4; ++it) {
            int slot = it * 256 + tid;
            int o = slot * 16;
            int r = o >> 7;
            int cb = o & 127;
            int scb = cb ^ ((r & 7) << 4);
            size_t j = (size_t)t * 256 + ks * 64 + (scb >> 1);
            gl16(kts + (size_t)(h * 128 + r) * 4096 + j, (char*)Kc + o);
            gl16(vt + (size_t)(h * 128 + r) * 4096 + j, (char*)Vc + o);
        }
        __syncthreads();
#pragma unroll
        for (int kk = 0; kk < 2; ++kk) {
            int kb = kk * 64 + ((lane >> 4) * 16);
            bf16x8 vf[2], kf[8];
#pragma unroll
            for (int m = 0; m < 2; ++m) {
                int e = w * 32 + m * 16 + (lane & 15);
                vf[m] = *(const bf16x8*)((const char*)Vc + (e << 7) + (kb ^ ((e & 7) << 4)));
            }
#pragma unroll
            for (int n = 0; n < 8; ++n) {
                int d = n * 16 + (lane & 15);
                kf[n] = *(const bf16x8*)((const char*)Kc + (d << 7) + (kb ^ ((d & 7) << 4)));
            }
#pragma unroll
            for (int m = 0; m < 2; ++m)
#pragma unroll
                for (int n = 0; n < 8; ++n)
                    acc[m][n] = MFMA16(vf[m], kf[n], acc[m][n]);
        }
    }
    size_t base = (size_t)(h * 16 + t) * 16384;
#pragma unroll
    for (int m = 0; m < 2; ++m)
#pragma unroll
        for (int n = 0; n < 8; ++n)
#pragma unroll
            for (int r = 0; r < 4; ++r) {
                int e = w * 32 + m * 16 + ((lane >> 4) * 4) + r;
                int d = n * 16 + (lane & 15);
                U[base + (size_t)e * 128 + d] = f2bf(acc[m][n][r]);
            }
}

// ---------- parallel scan: 32 heads x 16 chunks of 1024 (bf16 U in) ---------
__global__ __launch_bounds__(256) void kv_scan_kernel(const float* __restrict__ kv_cache,
                                                      const unsigned short* __restrict__ U,
                                                      const float* __restrict__ slopes,
                                                      unsigned short* __restrict__ Wb) {
    __shared__ float Tt[8][132];
    int h = blockIdx.x >> 4;
    int c = blockIdx.x & 15;
    int c0 = c * 1024, e0 = c * 8;
    int tid = threadIdx.x;
    float s = slopes[h];
    float bd = __expf(-s * 256.f);
    size_t hb = (size_t)h * 16384;
#pragma unroll
    for (int it = 0; it < 4; ++it) {
        int d = it * 32 + (tid >> 3);
        Tt[tid & 7][d] = kv_cache[hb + (size_t)d * 128 + e0 + (tid & 7)];
    }
    __syncthreads();
    float wst[4];
#pragma unroll
    for (int i = 0; i < 4; ++i) {
        int local = i * 256 + tid;
        wst[i] = Tt[local >> 7][local & 127];
    }
    for (int t = 0; t < 16; ++t) {
        size_t base = (size_t)(h * 16 + t) * 16384 + c0;
#pragma unroll
        for (int i = 0; i < 4; ++i) {
            int idx = i * 256 + tid;
            Wb[base + idx] = f2bf(wst[i]);
            if (t < 15) wst[i] = bd * wst[i] + bf2f(U[base + idx]);
        }
    }
}

// ---------- fused attention block kernel: QBLK=128, 80KB LDS, 2 WG/CU ----------
__global__ __launch_bounds__(256, 2) void attn_out_kernel(const unsigned short* __restrict__ qkv,
                                                          const unsigned short* __restrict__ vt,
                                                          const unsigned short* __restrict__ Wb,
                                                          const float* __restrict__ slopes,
                                                          unsigned short* __restrict__ attn) {
    __shared__ unsigned short lds[40960];  // 80 KB
    unsigned short* Qs = lds;
    unsigned short* Ps = lds + 16384;
    unsigned short* KW = lds + 24576;
    unsigned short* Ks = KW;
    unsigned short* Vs = KW + 8192;

    int blk = blockIdx.x;
    int h = blk & 31, tq = blk >> 5;
    int t = tq >> 1, qh = tq & 1;
    float s = slopes[h];
    int tid = threadIdx.x, lane = tid & 63, w = tid >> 6;
    int rowbase = t * 256 + qh * 128;

#pragma unroll
    for (int it = 0; it < 8; ++it) {
        int o = (it * 256 + tid) * 16;
        int r = o >> 8, cb = o & 255, scb = cb ^ ((r & 7) << 4);
        gl16(qkv + (size_t)(rowbase + r) * 12288 + h * 384 + (scb >> 1), (char*)Qs + o);
    }
#pragma unroll
    for (int it = 0; it < 8; ++it) {
        int o = (it * 256 + tid) * 16;
        int e = o >> 8, cb = o & 255, scb = cb ^ ((e & 7) << 4);
        gl16(Wb + (size_t)((h * 16 + t) * 128 + e) * 128 + (scb >> 1), (char*)KW + o);
    }
    __syncthreads();

    f32x4 acc[2][8];
#pragma unroll
    for (int m = 0; m < 2; ++m)
#pragma unroll
        for (int n = 0; n < 8; ++n)
#pragma unroll
            for (int r = 0; r < 4; ++r) acc[m][n][r] = 0.f;

#pragma unroll
    for (int kk = 0; kk < 4; ++kk) {
        int kb = kk * 64 + ((lane >> 4) * 16);
        bf16x8 qf[2], wf[8];
#pragma unroll
        for (int m = 0; m < 2; ++m) {
            int r = w * 32 + m * 16 + (lane & 15);
            qf[m] = *(const bf16x8*)((const char*)Qs + (r << 8) + (kb ^ ((r & 7) << 4)));
        }
#pragma unroll
        for (int n = 0; n < 8; ++n) {
            int e = n * 16 + (lane & 15);
            wf[n] = *(const bf16x8*)((const char*)KW + (e << 8) + (kb ^ ((e & 7) << 4)));
        }
#pragma unroll
        for (int m = 0; m < 2; ++m)
#pragma unroll
            for (int n = 0; n < 8; ++n)
                acc[m][n] = MFMA16(qf[m], wf[n], acc[m][n]);
    }
#pragma unroll
    for (int m = 0; m < 2; ++m)
#pragma unroll
        for (int rg = 0; rg < 4; ++rg) {
            int i = qh * 128 + w * 32 + m * 16 + ((lane >> 4) * 4) + rg;
            float qd = __expf(-s * (float)(i + 1));
#pragma unroll
            for (int n = 0; n < 8; ++n) acc[m][n][rg] *= qd;
        }

    int jbmax = ((qh << 2) + w) >> 1;
    for (int jb = 0; jb < 4; ++jb) {
        __syncthreads();
#pragma unroll
        for (int it = 0; it < 4; ++it) {
            int o = (it * 256 + tid) * 16;
            int r = o >> 8, cb = o & 255, scb = cb ^ ((r & 7) << 4);
            gl16(qkv + (size_t)(t * 256 + jb * 64 + r) * 12288 + h * 384 + 128 + (scb >> 1),
                 (char*)Ks + o);
        }
#pragma unroll
        for (int it = 0; it < 4; ++it) {
            int o = (it * 256 + tid) * 16;
            int e = o >> 7, cb = o & 127, scb = cb ^ ((e & 7) << 4);
            gl16(vt + (size_t)(h * 128 + e) * 4096 + t * 256 + jb * 64 + (scb >> 1),
                 (char*)Vs + o);
        }
        __syncthreads();

        if (jb <= jbmax) {
            f32x4 sc[2][4];
#pragma unroll
            for (int m = 0; m < 2; ++m)
#pragma unroll
                for (int n = 0; n < 4; ++n)
#pragma unroll
                    for (int r = 0; r < 4; ++r) sc[m][n][r] = 0.f;
#pragma unroll
            for (int kk = 0; kk < 4; ++kk) {
                int kb = kk * 64 + ((lane >> 4) * 16);
                bf16x8 qf[2], kf[4];
#pragma unroll
                for (int m = 0; m < 2; ++m) {
                    int r = w * 32 + m * 16 + (lane & 15);
                    qf[m] = *(const bf16x8*)((const char*)Qs + (r << 8) + (kb ^ ((r & 7) << 4)));
                }
#pragma unroll
                for (int n = 0; n < 4; ++n) {
                    int r = n * 16 + (lane & 15);
                    kf[n] = *(const bf16x8*)((const char*)Ks + (r << 8) + (kb ^ ((r & 7) << 4)));
                }
#pragma unroll
                for (int m = 0; m < 2; ++m)
#pragma unroll
                    for (int n = 0; n < 4; ++n)
                        sc[m][n] = MFMA16(qf[m], kf[n], sc[m][n]);
            }
            unsigned short* Pw = Ps + w * 2048;
#pragma unroll
            for (int m = 0; m < 2; ++m)
#pragma unroll
                for (int n = 0; n < 4; ++n)
#pragma unroll
                    for (int rg = 0; rg < 4; ++rg) {
                        int il = m * 16 + ((lane >> 4) * 4) + rg;
                        int i = qh * 128 + w * 32 + il;
                        int jl = n * 16 + (lane & 15);
                        int j = jb * 64 + jl;
                        float v = 0.f;
                        if (i >= j) v = sc[m][n][rg] * __expf(-s * (float)(i - j));
                        int cb2 = (jl * 2) ^ ((il & 7) << 4);
                        *(unsigned short*)((char*)Pw + (il << 7) + cb2) = f2bf(v);
                    }
            asm volatile("s_waitcnt lgkmcnt(0)" ::: "memory");
#pragma unroll
            for (int kk = 0; kk < 2; ++kk) {
                int kb = kk * 64 + ((lane >> 4) * 16);
                bf16x8 pf[2], vf[8];
#pragma unroll
                for (int m = 0; m < 2; ++m) {
                    int il = m * 16 + (lane & 15);
                    pf[m] = *(const bf16x8*)((const char*)Pw + (il << 7) + (kb ^ ((il & 7) << 4)));
                }
#pragma unroll
                for (int n = 0; n < 8; ++n) {
                    int e = n * 16 + (lane & 15);
                    vf[n] = *(const bf16x8*)((const char*)Vs + (e << 7) + (kb ^ ((e & 7) << 4)));
                }
#pragma unroll
                for (int m = 0; m < 2; ++m)
#pragma unroll
                    for (int n = 0; n < 8; ++n)
                        acc[m][n] = MFMA16(pf[m], vf[n], acc[m][n]);
            }
        }
    }

#pragma unroll
    for (int m = 0; m < 2; ++m)
#pragma unroll
        for (int n = 0; n < 8; ++n)
#pragma unroll
            for (int rg = 0; rg < 4; ++rg) {
                int i = qh * 128 + w * 32 + m * 16 + ((lane >> 4) * 4) + rg;
                int col = h * 128 + n * 16 + (lane & 15);
                attn[(size_t)(t * 256 + i) * 4096 + col] = f2bf(acc[m][n][rg]);
            }
}

// ---------- RMSNorm + sigmoid-gate multiply ----------
__global__ __launch_bounds__(256) void rms_gate_kernel(const unsigned short* __restrict__ attn,
                                                       const unsigned short* __restrict__ gate,
                                                       const float* __restrict__ nw,
                                                       unsigned short* __restrict__ gated) {
    int row = blockIdx.x, tid = threadIdx.x;
    int lane = tid & 63, w = tid >> 6;
    const unsigned short* ar = attn + (size_t)row * 4096 + tid * 16;
    u16x8 a0 = *(const u16x8*)ar;
    u16x8 a1 = *(const u16x8*)(ar + 8);
    float v[16];
    float ss = 0.f;
#pragma unroll
    for (int j = 0; j < 8; ++j) { v[j] = bf2f(a0[j]); v[8 + j] = bf2f(a1[j]); }
#pragma unroll
    for (int j = 0; j < 16; ++j) ss += v[j] * v[j];
#pragma unroll
    for (int o = 32; o > 0; o >>= 1) ss += __shfl_xor(ss, o);
    __shared__ float red[4];
    if (lane == 0) red[w] = ss;
    __syncthreads();
    float tot = red[0] + red[1] + red[2] + red[3];
    float rs = rsqrtf(tot * (1.f / 4096.f) + 1e-5f);
    const unsigned short* gr = gate + (size_t)row * 4096 + tid * 16;
    u16x8 g0 = *(const u16x8*)gr;
    u16x8 g1 = *(const u16x8*)(gr + 8);
    const float* nwp = nw + tid * 16;
    u16x8 o0, o1;
#pragma unroll
    for (int j = 0; j < 8; ++j) {
        o0[j] = f2bf(v[j] * rs * nwp[j] * bf2f(g0[j]));
        o1[j] = f2bf(v[8 + j] * rs * nwp[8 + j] * bf2f(g1[j]));
    }
    unsigned short* gp = gated + (size_t)row * 4096 + tid * 16;
    *(u16x8*)gp = o0;
    *(u16x8*)(gp + 8) = o1;
}

// ---------- launcher ----------
extern "C" void kernel_launch(void* const* d_in, const int* in_sizes, int n_in,
                              void* d_out, int out_size, void* d_ws, size_t ws_size,
                              hipStream_t stream) {
    const float* hs       = (const float*)d_in[0];
    const float* w_qkv    = (const float*)d_in[1];
    const float* w_gate   = (const float*)d_in[2];
    const float* w_out    = (const float*)d_in[3];
    const float* nw       = (const float*)d_in[4];
    const float* slopes   = (const float*)d_in[5];
    const float* kv_cache = (const float*)d_in[6];
    float* out = (float*)d_out;
    char* ws = (char*)d_ws;

    unsigned short* hsb  = (unsigned short*)(ws + 0);
    unsigned short* wqt  = (unsigned short*)(ws + 16777216);
    unsigned short* wgt  = (unsigned short*)(ws + 67108864);
    unsigned short* wot  = (unsigned short*)(ws + 83886080);
    unsigned short* qkv  = (unsigned short*)(ws + 100663296);
    unsigned short* gate = (unsigned short*)(ws + 201326592);
    unsigned short* kts  = (unsigned short*)(ws + 234881024);
    unsigned short* vt   = (unsigned short*)(ws + 268435456);
    unsigned short* U    = (unsigned short*)(ws + 301989888);  // 16 MB bf16
    unsigned short* Wb   = (unsigned short*)(ws + 335544320);
    unsigned short* attn  = wqt;  // reuse
    unsigned short* gated = qkv;  // reuse

    prep_kernel<<<14336, 256, 0, stream>>>(hs, w_qkv, w_gate, w_out, hsb, wqt, wgt, wot);
    gemm_qkvgate_kernel<<<1024, 512, 0, stream>>>(hsb, wqt, qkv, gate, 2048, 64, 48);
    {
        dim3 g(64, 2, 32);
        kv_transpose_kernel<<<g, 256, 0, stream>>>(qkv, slopes, kts, vt);
    }
    kv_outer_kernel<<<480, 256, 0, stream>>>(kts, vt, U);
    kv_scan_kernel<<<512, 256, 0, stream>>>(kv_cache, U, slopes, Wb);
    attn_out_kernel<<<1024, 256, 0, stream>>>(qkv, vt, Wb, slopes, attn);
    rms_gate_kernel<<<4096, 256, 0, stream>>>(attn, gate, nw, gated);
    gemm_out_kernel<<<512, 256, 0, stream>>>(gated, wot, out, 2048, 4096, 16);
}